// Round 1
// baseline (6610.884 us; speedup 1.0000x reference)
//
#include <hip/hip_runtime.h>
#include <cstddef>

#define LN_EPS 1e-5f

// ---------------------------------------------------------------------------
// Tiled fp32 GEMM:  C[M,N] = dotScale*(A[M,K] @ B[N,K]^T + bias[N]) + res1 + res2
// Optional ReLU. All M,N multiples of 64; K multiple of 32.
// ---------------------------------------------------------------------------
template<bool RELU>
__global__ __launch_bounds__(256) void gemm_nt(
    const float* __restrict__ A, const float* __restrict__ B,
    const float* __restrict__ bias,
    const float* __restrict__ res1, const float* __restrict__ res2,
    float dotScale, float* __restrict__ C, int M, int N, int K)
{
    __shared__ float As[64][33];
    __shared__ float Bs[64][33];
    const int tid = threadIdx.x;
    const int tx = tid & 15, ty = tid >> 4;
    const int m0 = blockIdx.y * 64, n0 = blockIdx.x * 64;

    float acc[4][4] = {};

    for (int k0 = 0; k0 < K; k0 += 32) {
#pragma unroll
        for (int it = 0; it < 2; ++it) {
            int idx = tid + it * 256;          // 0..511  (64 rows x 8 float4)
            int r = idx >> 3, c4 = (idx & 7) * 4;
            const float4 va = *(const float4*)&A[(size_t)(m0 + r) * K + k0 + c4];
            As[r][c4 + 0] = va.x; As[r][c4 + 1] = va.y;
            As[r][c4 + 2] = va.z; As[r][c4 + 3] = va.w;
            const float4 vb = *(const float4*)&B[(size_t)(n0 + r) * K + k0 + c4];
            Bs[r][c4 + 0] = vb.x; Bs[r][c4 + 1] = vb.y;
            Bs[r][c4 + 2] = vb.z; Bs[r][c4 + 3] = vb.w;
        }
        __syncthreads();
#pragma unroll
        for (int k = 0; k < 32; ++k) {
            float a[4], b[4];
#pragma unroll
            for (int i = 0; i < 4; ++i) a[i] = As[ty * 4 + i][k];
#pragma unroll
            for (int j = 0; j < 4; ++j) b[j] = Bs[tx * 4 + j][k];
#pragma unroll
            for (int i = 0; i < 4; ++i)
#pragma unroll
                for (int j = 0; j < 4; ++j) acc[i][j] += a[i] * b[j];
        }
        __syncthreads();
    }

#pragma unroll
    for (int i = 0; i < 4; ++i) {
        const int row = m0 + ty * 4 + i;
        const int col = n0 + tx * 4;
        float v[4];
#pragma unroll
        for (int j = 0; j < 4; ++j) v[j] = dotScale * (acc[i][j] + bias[col + j]);
        if (res1) {
            const float4 r1 = *(const float4*)&res1[(size_t)row * N + col];
            v[0] += r1.x; v[1] += r1.y; v[2] += r1.z; v[3] += r1.w;
        }
        if (res2) {
            const float4 r2 = *(const float4*)&res2[(size_t)row * N + col];
            v[0] += r2.x; v[1] += r2.y; v[2] += r2.z; v[3] += r2.w;
        }
        if (RELU) {
#pragma unroll
            for (int j = 0; j < 4; ++j) v[j] = fmaxf(v[j], 0.f);
        }
        float4 st; st.x = v[0]; st.y = v[1]; st.z = v[2]; st.w = v[3];
        *(float4*)&C[(size_t)row * N + col] = st;
    }
}

// ---------------------------------------------------------------------------
// Attention core. One block per query token (r = i*2 + b). Loops over 8 heads:
// scores = q_h . K_h^T * 0.125 -> softmax -> out_h = P @ V_h.
// Optionally accumulates head-averaged probs into wavg[(b*L+i)*S + s].
// Token row layout: row = seqpos*2 + batch; head h at columns h*64..h*64+63.
// ---------------------------------------------------------------------------
template<bool NEED_W>
__global__ __launch_bounds__(256) void attn_kern(
    const float* __restrict__ Q, int ldq,
    const float* __restrict__ Kp, int ldk,
    const float* __restrict__ Vp, int ldv,
    float* __restrict__ out,          // (L*2) x 512
    float* __restrict__ wavg,         // 2 x L x S (if NEED_W)
    int L, int S)
{
    __shared__ float q[512];
    __shared__ float sc[2048];
    __shared__ float wacc[2048];
    __shared__ float red[256];
    __shared__ float osum[256];

    const int r = blockIdx.x;          // i*2 + b
    const int i = r >> 1, b = r & 1;
    const int tid = threadIdx.x;

    for (int c = tid; c < 512; c += 256) q[c] = Q[(size_t)r * ldq + c];
    if (NEED_W)
        for (int s = tid; s < S; s += 256) wacc[s] = 0.f;
    __syncthreads();

    for (int h = 0; h < 8; ++h) {
        const float* qh = q + h * 64;
        // -------- scores
        float lmax = -1e30f;
        for (int s = tid; s < S; s += 256) {
            const float4* k4 = (const float4*)(Kp + (size_t)(s * 2 + b) * ldk + h * 64);
            float d = 0.f;
#pragma unroll
            for (int e = 0; e < 16; ++e) {
                const float4 kv = k4[e];
                const float4 qv = *(const float4*)&qh[e * 4];
                d += qv.x * kv.x + qv.y * kv.y + qv.z * kv.z + qv.w * kv.w;
            }
            d *= 0.125f;
            sc[s] = d;
            lmax = fmaxf(lmax, d);
        }
        red[tid] = lmax; __syncthreads();
        for (int st = 128; st; st >>= 1) {
            if (tid < st) red[tid] = fmaxf(red[tid], red[tid + st]);
            __syncthreads();
        }
        const float mx = red[0]; __syncthreads();
        // -------- exp + sum
        float lsum = 0.f;
        for (int s = tid; s < S; s += 256) {
            const float p = __expf(sc[s] - mx);
            sc[s] = p; lsum += p;
        }
        red[tid] = lsum; __syncthreads();
        for (int st = 128; st; st >>= 1) {
            if (tid < st) red[tid] += red[tid + st];
            __syncthreads();
        }
        const float inv = 1.0f / red[0]; __syncthreads();
        // -------- normalize (+ weight accumulation)
        for (int s = tid; s < S; s += 256) {
            const float p = sc[s] * inv;
            sc[s] = p;
            if (NEED_W) wacc[s] += p * 0.125f;   // 1/H
        }
        __syncthreads();
        // -------- P @ V_h   (64 dims, 4-way split over s)
        const int d = tid & 63, qtr = tid >> 6;
        const int chunk = S >> 2;
        float acc = 0.f;
        for (int s = qtr * chunk; s < (qtr + 1) * chunk; ++s)
            acc += sc[s] * Vp[(size_t)(s * 2 + b) * ldv + h * 64 + d];
        osum[tid] = acc; __syncthreads();
        if (tid < 64)
            out[(size_t)r * 512 + h * 64 + tid] =
                osum[tid] + osum[64 + tid] + osum[128 + tid] + osum[192 + tid];
        __syncthreads();
    }

    if (NEED_W)
        for (int s = tid; s < S; s += 256)
            wavg[((size_t)b * L + i) * S + s] = wacc[s];
}

// ---------------------------------------------------------------------------
// LayerNorm over rows of 512.
// ---------------------------------------------------------------------------
__global__ __launch_bounds__(256) void ln512(
    const float* __restrict__ X, const float* __restrict__ g,
    const float* __restrict__ be, float* __restrict__ Y)
{
    __shared__ float red[256];
    const int r = blockIdx.x, tid = threadIdx.x;
    const float* xr = X + (size_t)r * 512;
    const float x0 = xr[tid], x1 = xr[tid + 256];
    red[tid] = x0 + x1; __syncthreads();
    for (int st = 128; st; st >>= 1) {
        if (tid < st) red[tid] += red[tid + st];
        __syncthreads();
    }
    const float mean = red[0] * (1.0f / 512.0f); __syncthreads();
    const float d0 = x0 - mean, d1 = x1 - mean;
    red[tid] = d0 * d0 + d1 * d1; __syncthreads();
    for (int st = 128; st; st >>= 1) {
        if (tid < st) red[tid] += red[tid + st];
        __syncthreads();
    }
    const float rstd = rsqrtf(red[0] * (1.0f / 512.0f) + LN_EPS);
    float* yr = Y + (size_t)r * 512;
    yr[tid]       = d0 * rstd * g[tid] + be[tid];
    yr[tid + 256] = d1 * rstd * g[tid + 256] + be[tid + 256];
}

// ---------------------------------------------------------------------------
// Row softmax (second softmax on averaged weights); writes 1 or 2 outputs.
// ---------------------------------------------------------------------------
__global__ __launch_bounds__(256) void softmax_rows(
    const float* __restrict__ X, int S,
    float* __restrict__ out1, float* __restrict__ out2)
{
    __shared__ float sc[2048];
    __shared__ float red[256];
    const int r = blockIdx.x, tid = threadIdx.x;
    const float* xr = X + (size_t)r * S;
    float lmax = -1e30f;
    for (int s = tid; s < S; s += 256) {
        const float v = xr[s]; sc[s] = v; lmax = fmaxf(lmax, v);
    }
    red[tid] = lmax; __syncthreads();
    for (int st = 128; st; st >>= 1) {
        if (tid < st) red[tid] = fmaxf(red[tid], red[tid + st]);
        __syncthreads();
    }
    const float mx = red[0]; __syncthreads();
    float lsum = 0.f;
    for (int s = tid; s < S; s += 256) {
        const float p = __expf(sc[s] - mx); sc[s] = p; lsum += p;
    }
    red[tid] = lsum; __syncthreads();
    for (int st = 128; st; st >>= 1) {
        if (tid < st) red[tid] += red[tid + st];
        __syncthreads();
    }
    const float inv = 1.0f / red[0];
    for (int s = tid; s < S; s += 256) {
        const float p = sc[s] * inv;
        out1[(size_t)r * S + s] = p;
        if (out2) out2[(size_t)r * S + s] = p;
    }
}

// ---------------------------------------------------------------------------
// pair = entire_pair.at[ind_pair].set(sp) realized lazily via inverse map.
// ---------------------------------------------------------------------------
__global__ void init_inv(int* __restrict__ inv) {
    const int i = blockIdx.x * 256 + threadIdx.x;
    if (i < 4096) inv[i] = -1;
}
__global__ void scatter_inv(int* __restrict__ inv, const int* __restrict__ ind, int n) {
    const int i = blockIdx.x * 256 + threadIdx.x;
    if (i < n) inv[ind[i]] = i;
}
// dst rows (j*2+b) <- (inv[ind[j]]>=0 ? sp : entire_pair); 128 float4 per row
__global__ void gather_rows(
    float4* __restrict__ dst, const float4* __restrict__ sp,
    const float4* __restrict__ ep, const int* __restrict__ ind,
    const int* __restrict__ inv, int total4)
{
    const int e = blockIdx.x * 256 + threadIdx.x;
    if (e >= total4) return;
    const int row = e >> 7, c = e & 127;
    const int j = row >> 1, b = row & 1;
    const int idx = ind[j];
    const int iv = inv[idx];
    const float4* src = (iv >= 0) ? (sp + (size_t)(iv * 2 + b) * 128)
                                  : (ep + (size_t)(idx * 2 + b) * 128);
    dst[e] = src[c];
}

// ---------------------------------------------------------------------------
extern "C" void kernel_launch(void* const* d_in, const int* in_sizes, int n_in,
                              void* d_out, int out_size, void* d_ws, size_t ws_size,
                              hipStream_t stream)
{
    (void)in_sizes; (void)n_in; (void)out_size; (void)ws_size;

    const float* in_sp = (const float*)d_in[0];   // (1024,2,512)
    const float* in_su = (const float*)d_in[1];   // (256,2,512)
    const float* in_ep = (const float*)d_in[2];   // (4096,2,512)
    const int* ind_pair = (const int*)d_in[3];
    const int* ind_e2e  = (const int*)d_in[4];
    const int* ind_n2e  = (const int*)d_in[5];
    const float *Wi_sa  = (const float*)d_in[6],  *bi_sa  = (const float*)d_in[7];
    const float *Wo_sa  = (const float*)d_in[8],  *bo_sa  = (const float*)d_in[9];
    const float *Wi_san = (const float*)d_in[10], *bi_san = (const float*)d_in[11];
    const float *Wo_san = (const float*)d_in[12], *bo_san = (const float*)d_in[13];
    const float *Wi_e2e = (const float*)d_in[14], *bi_e2e = (const float*)d_in[15];
    const float *Wo_e2e = (const float*)d_in[16], *bo_e2e = (const float*)d_in[17];
    const float *Wi_n2e = (const float*)d_in[18], *bi_n2e = (const float*)d_in[19];
    const float *Wo_n2e = (const float*)d_in[20], *bo_n2e = (const float*)d_in[21];
    const float *Wi_n2n = (const float*)d_in[22], *bi_n2n = (const float*)d_in[23];
    const float *Wo_n2n = (const float*)d_in[24], *bo_n2n = (const float*)d_in[25];
    const float *W1  = (const float*)d_in[26], *b1f  = (const float*)d_in[27];
    const float *W2  = (const float*)d_in[28], *b2f  = (const float*)d_in[29];
    const float *W1u = (const float*)d_in[30], *b1fu = (const float*)d_in[31];
    const float *W2u = (const float*)d_in[32], *b2fu = (const float*)d_in[33];
    const float *g1  = (const float*)d_in[34], *g1u = (const float*)d_in[35];
    const float *g2  = (const float*)d_in[36], *g3  = (const float*)d_in[37];
    const float *be1 = (const float*)d_in[38], *be1u = (const float*)d_in[39];
    const float *be2 = (const float*)d_in[40], *be3  = (const float*)d_in[41];

    // workspace layout (floats)
    float* W = (float*)d_ws;
    size_t o = 0;
    auto alloc = [&](size_t n) { float* p = W + o; o += n; return p; };
    float* sp    = alloc((size_t)2048 * 512);
    float* su    = alloc((size_t)512 * 512);
    float* ge2e  = alloc((size_t)4096 * 512);
    float* gn2e  = alloc((size_t)4096 * 512);
    float* qkv   = alloc((size_t)2048 * 1536);
    float* kv    = alloc((size_t)4096 * 1024);
    float* att   = alloc((size_t)2048 * 512);
    float* tmp0  = alloc((size_t)2048 * 512);
    float* tmp1  = alloc((size_t)2048 * 512);
    float* ffnh  = alloc((size_t)2048 * 2048);
    float* upn2e = alloc((size_t)512 * 512);
    float* w_e2e = alloc((size_t)2 * 1024 * 2048);
    float* w_n2e = alloc((size_t)2 * 256 * 2048);
    float* w_n2n = alloc((size_t)2 * 256 * 256);
    int*   inv   = (int*)(W + o);

    float* out_uu = (float*)d_out;                 // updated_unary (256,2,512)
    float* out_up = out_uu + 262144;               // updated_pair (1024,2,512)
    float* out_w1 = out_up + 1048576;              // w_e2e  (2,1024,2048)
    float* out_w2 = out_w1 + 4194304;              // w_e2e again
    float* out_w3 = out_w2 + 4194304;              // w_n2e  (2,256,2048)
    float* out_w4 = out_w3 + 1048576;              // w_n2n  (2,256,256)

    const dim3 blk(256);
    auto gemm = [&](const float* A, const float* B, const float* bias,
                    const float* r1, const float* r2, float scale, bool relu,
                    float* C, int M, int N, int K) {
        dim3 grid(N / 64, M / 64);
        if (relu)
            gemm_nt<true><<<grid, blk, 0, stream>>>(A, B, bias, r1, r2, scale, C, M, N, K);
        else
            gemm_nt<false><<<grid, blk, 0, stream>>>(A, B, bias, r1, r2, scale, C, M, N, K);
    };

    // inverse scatter map for pair assembly
    init_inv<<<16, blk, 0, stream>>>(inv);
    scatter_inv<<<4, blk, 0, stream>>>(inv, ind_pair, 1024);

    // ---- self-attention on sparsified_pair -> sp
    gemm(in_sp, Wi_sa, bi_sa, nullptr, nullptr, 1.f, false, qkv, 2048, 1536, 512);
    attn_kern<false><<<2048, blk, 0, stream>>>(qkv, 1536, qkv + 512, 1536, qkv + 1024, 1536,
                                               att, nullptr, 1024, 1024);
    gemm(att, Wo_sa, bo_sa, in_sp, nullptr, 1.f, false, tmp0, 2048, 512, 512);
    ln512<<<2048, blk, 0, stream>>>(tmp0, g1, be1, sp);

    // ---- self-attention on sparsified_unary -> su
    gemm(in_su, Wi_san, bi_san, nullptr, nullptr, 1.f, false, qkv, 512, 1536, 512);
    attn_kern<false><<<512, blk, 0, stream>>>(qkv, 1536, qkv + 512, 1536, qkv + 1024, 1536,
                                              att, nullptr, 256, 256);
    gemm(att, Wo_san, bo_san, in_su, nullptr, 1.f, false, tmp0, 512, 512, 512);
    ln512<<<512, blk, 0, stream>>>(tmp0, g1u, be1u, su);

    // ---- gathers: pair_e2e, pair_n2e
    gather_rows<<<2048, blk, 0, stream>>>((float4*)ge2e, (const float4*)sp,
                                          (const float4*)in_ep, ind_e2e, inv, 524288);
    gather_rows<<<2048, blk, 0, stream>>>((float4*)gn2e, (const float4*)sp,
                                          (const float4*)in_ep, ind_n2e, inv, 524288);

    // ---- e2e cross-attention: q=sp, kv=pair_e2e
    gemm(sp, Wi_e2e, bi_e2e, nullptr, nullptr, 1.f, false, qkv, 2048, 512, 512);
    gemm(ge2e, Wi_e2e + 512 * 512, bi_e2e + 512, nullptr, nullptr, 1.f, false, kv, 4096, 1024, 512);
    attn_kern<true><<<2048, blk, 0, stream>>>(qkv, 512, kv, 1024, kv + 512, 1024,
                                              att, w_e2e, 1024, 2048);
    gemm(att, Wo_e2e, bo_e2e, sp, nullptr, 2.f, false, tmp0, 2048, 512, 512);  // sp + 2*up_e2e
    ln512<<<2048, blk, 0, stream>>>(tmp0, g2, be2, tmp1);
    // FFN (pair)
    gemm(tmp1, W1, b1f, nullptr, nullptr, 1.f, true, ffnh, 2048, 2048, 512);
    gemm(ffnh, W2, b2f, tmp1, nullptr, 1.f, false, tmp0, 2048, 512, 2048);
    ln512<<<2048, blk, 0, stream>>>(tmp0, g3, be3, out_up);

    // ---- n2e cross-attention: q=su, kv=pair_n2e
    gemm(su, Wi_n2e, bi_n2e, nullptr, nullptr, 1.f, false, qkv, 512, 512, 512);
    gemm(gn2e, Wi_n2e + 512 * 512, bi_n2e + 512, nullptr, nullptr, 1.f, false, kv, 4096, 1024, 512);
    attn_kern<true><<<512, blk, 0, stream>>>(qkv, 512, kv, 1024, kv + 512, 1024,
                                             att, w_n2e, 256, 2048);
    gemm(att, Wo_n2e, bo_n2e, nullptr, nullptr, 1.f, false, upn2e, 512, 512, 512);

    // ---- n2n self-attention on su
    gemm(su, Wi_n2n, bi_n2n, nullptr, nullptr, 1.f, false, qkv, 512, 1536, 512);
    attn_kern<true><<<512, blk, 0, stream>>>(qkv, 1536, qkv + 512, 1536, qkv + 1024, 1536,
                                             att, w_n2n, 256, 256);
    gemm(att, Wo_n2n, bo_n2n, su, upn2e, 1.f, false, tmp0, 512, 512, 512); // su+up_n2e+up_n2n
    ln512<<<512, blk, 0, stream>>>(tmp0, g2, be2, tmp1);
    // FFN (unary)
    gemm(tmp1, W1u, b1fu, nullptr, nullptr, 1.f, true, ffnh, 512, 2048, 512);
    gemm(ffnh, W2u, b2fu, tmp1, nullptr, 1.f, false, tmp0, 512, 512, 2048);
    ln512<<<512, blk, 0, stream>>>(tmp0, g3, be3, out_uu);

    // ---- second softmax on averaged weights -> outputs
    softmax_rows<<<2048, blk, 0, stream>>>(w_e2e, 2048, out_w1, out_w2);
    softmax_rows<<<512, blk, 0, stream>>>(w_n2e, 2048, out_w3, nullptr);
    softmax_rows<<<512, blk, 0, stream>>>(w_n2n, 256, out_w4, nullptr);
}

// Round 2
// 1790.668 us; speedup vs baseline: 3.6919x; 3.6919x over previous
//
#include <hip/hip_runtime.h>
#include <cstddef>

#define LN_EPS 1e-5f

// ---------------------------------------------------------------------------
// Tiled fp32 GEMM:  C[M,N] = dotScale*(A[M,K] @ B[N,K]^T + bias[N]) + res1 + res2
// Optional ReLU. All M,N multiples of 64; K multiple of 32.
// ---------------------------------------------------------------------------
template<bool RELU>
__global__ __launch_bounds__(256) void gemm_nt(
    const float* __restrict__ A, const float* __restrict__ B,
    const float* __restrict__ bias,
    const float* __restrict__ res1, const float* __restrict__ res2,
    float dotScale, float* __restrict__ C, int M, int N, int K)
{
    __shared__ float As[64][33];
    __shared__ float Bs[64][33];
    const int tid = threadIdx.x;
    const int tx = tid & 15, ty = tid >> 4;
    const int m0 = blockIdx.y * 64, n0 = blockIdx.x * 64;

    float acc[4][4] = {};

    for (int k0 = 0; k0 < K; k0 += 32) {
#pragma unroll
        for (int it = 0; it < 2; ++it) {
            int idx = tid + it * 256;          // 0..511  (64 rows x 8 float4)
            int r = idx >> 3, c4 = (idx & 7) * 4;
            const float4 va = *(const float4*)&A[(size_t)(m0 + r) * K + k0 + c4];
            As[r][c4 + 0] = va.x; As[r][c4 + 1] = va.y;
            As[r][c4 + 2] = va.z; As[r][c4 + 3] = va.w;
            const float4 vb = *(const float4*)&B[(size_t)(n0 + r) * K + k0 + c4];
            Bs[r][c4 + 0] = vb.x; Bs[r][c4 + 1] = vb.y;
            Bs[r][c4 + 2] = vb.z; Bs[r][c4 + 3] = vb.w;
        }
        __syncthreads();
#pragma unroll
        for (int k = 0; k < 32; ++k) {
            float a[4], b[4];
#pragma unroll
            for (int i = 0; i < 4; ++i) a[i] = As[ty * 4 + i][k];
#pragma unroll
            for (int j = 0; j < 4; ++j) b[j] = Bs[tx * 4 + j][k];
#pragma unroll
            for (int i = 0; i < 4; ++i)
#pragma unroll
                for (int j = 0; j < 4; ++j) acc[i][j] += a[i] * b[j];
        }
        __syncthreads();
    }

#pragma unroll
    for (int i = 0; i < 4; ++i) {
        const int row = m0 + ty * 4 + i;
        const int col = n0 + tx * 4;
        float v[4];
#pragma unroll
        for (int j = 0; j < 4; ++j) v[j] = dotScale * (acc[i][j] + bias[col + j]);
        if (res1) {
            const float4 r1 = *(const float4*)&res1[(size_t)row * N + col];
            v[0] += r1.x; v[1] += r1.y; v[2] += r1.z; v[3] += r1.w;
        }
        if (res2) {
            const float4 r2 = *(const float4*)&res2[(size_t)row * N + col];
            v[0] += r2.x; v[1] += r2.y; v[2] += r2.z; v[3] += r2.w;
        }
        if (RELU) {
#pragma unroll
            for (int j = 0; j < 4; ++j) v[j] = fmaxf(v[j], 0.f);
        }
        float4 st; st.x = v[0]; st.y = v[1]; st.z = v[2]; st.w = v[3];
        *(float4*)&C[(size_t)row * N + col] = st;
    }
}

// ---------------------------------------------------------------------------
// Attention scores as batched GEMM over (b,h):
//   P[bh][i][s] = 0.125 * dot(Q_h(i), K_h(s))   bh = h*2+b
// Token rows: r = seqpos*2 + b; head h at columns h*64..h*64+63.
// Grid: (S/64, L/64, 16).
// ---------------------------------------------------------------------------
__global__ __launch_bounds__(256) void attn_score(
    const float* __restrict__ Q, int ldq,
    const float* __restrict__ Kp, int ldk,
    float* __restrict__ P, int L, int S)
{
    __shared__ float As[64][65];
    __shared__ float Bs[64][65];
    const int tid = threadIdx.x;
    const int tx = tid & 15, ty = tid >> 4;
    const int s0 = blockIdx.x * 64, i0 = blockIdx.y * 64;
    const int bh = blockIdx.z;
    const int b = bh & 1, h = bh >> 1;

#pragma unroll
    for (int it = 0; it < 4; ++it) {
        int idx = tid + it * 256;           // 64 rows x 16 float4
        int r = idx >> 4, c4 = (idx & 15) * 4;
        const float4 va = *(const float4*)&Q[(size_t)((i0 + r) * 2 + b) * ldq + h * 64 + c4];
        As[r][c4 + 0] = va.x; As[r][c4 + 1] = va.y;
        As[r][c4 + 2] = va.z; As[r][c4 + 3] = va.w;
        const float4 vb = *(const float4*)&Kp[(size_t)((s0 + r) * 2 + b) * ldk + h * 64 + c4];
        Bs[r][c4 + 0] = vb.x; Bs[r][c4 + 1] = vb.y;
        Bs[r][c4 + 2] = vb.z; Bs[r][c4 + 3] = vb.w;
    }
    __syncthreads();

    float acc[4][4] = {};
#pragma unroll
    for (int k = 0; k < 64; ++k) {
        float a[4], bb[4];
#pragma unroll
        for (int i = 0; i < 4; ++i) a[i] = As[ty * 4 + i][k];
#pragma unroll
        for (int j = 0; j < 4; ++j) bb[j] = Bs[tx * 4 + j][k];
#pragma unroll
        for (int i = 0; i < 4; ++i)
#pragma unroll
            for (int j = 0; j < 4; ++j) acc[i][j] += a[i] * bb[j];
    }

    float* Pb = P + (size_t)bh * L * S;
#pragma unroll
    for (int i = 0; i < 4; ++i) {
        float4 st;
        st.x = acc[i][0] * 0.125f; st.y = acc[i][1] * 0.125f;
        st.z = acc[i][2] * 0.125f; st.w = acc[i][3] * 0.125f;
        *(float4*)&Pb[(size_t)(i0 + ty * 4 + i) * S + s0 + tx * 4] = st;
    }
}

// ---------------------------------------------------------------------------
// P @ V per (b,h):  out[(i*2+b)*512 + h*64 + d] = sum_s P[bh][i][s] * V_h(s)[d]
// Grid: (L/64, 16).
// ---------------------------------------------------------------------------
__global__ __launch_bounds__(256) void attn_pv(
    const float* __restrict__ P,
    const float* __restrict__ Vp, int ldv,
    float* __restrict__ out, int L, int S)
{
    __shared__ float Ps[64][65];
    __shared__ float Vs[64][65];
    const int tid = threadIdx.x;
    const int tx = tid & 15, ty = tid >> 4;
    const int i0 = blockIdx.x * 64;
    const int bh = blockIdx.y;
    const int b = bh & 1, h = bh >> 1;
    const float* Pb = P + (size_t)bh * L * S;

    float acc[4][4] = {};
    for (int k0 = 0; k0 < S; k0 += 64) {
#pragma unroll
        for (int it = 0; it < 4; ++it) {
            int idx = tid + it * 256;
            int r = idx >> 4, c4 = (idx & 15) * 4;
            const float4 vp = *(const float4*)&Pb[(size_t)(i0 + r) * S + k0 + c4];
            Ps[r][c4 + 0] = vp.x; Ps[r][c4 + 1] = vp.y;
            Ps[r][c4 + 2] = vp.z; Ps[r][c4 + 3] = vp.w;
            const float4 vv = *(const float4*)&Vp[(size_t)((k0 + r) * 2 + b) * ldv + h * 64 + c4];
            Vs[r][c4 + 0] = vv.x; Vs[r][c4 + 1] = vv.y;
            Vs[r][c4 + 2] = vv.z; Vs[r][c4 + 3] = vv.w;
        }
        __syncthreads();
#pragma unroll
        for (int k = 0; k < 64; ++k) {
            float a[4], v[4];
#pragma unroll
            for (int i = 0; i < 4; ++i) a[i] = Ps[ty * 4 + i][k];
#pragma unroll
            for (int j = 0; j < 4; ++j) v[j] = Vs[k][tx * 4 + j];
#pragma unroll
            for (int i = 0; i < 4; ++i)
#pragma unroll
                for (int j = 0; j < 4; ++j) acc[i][j] += a[i] * v[j];
        }
        __syncthreads();
    }

#pragma unroll
    for (int i = 0; i < 4; ++i) {
        float4 st; st.x = acc[i][0]; st.y = acc[i][1]; st.z = acc[i][2]; st.w = acc[i][3];
        *(float4*)&out[(size_t)((i0 + ty * 4 + i) * 2 + b) * 512 + h * 64 + tx * 4] = st;
    }
}

// ---------------------------------------------------------------------------
// wavg[b][i][s] = (1/8) * sum_h P[h*2+b][i][s]
// ---------------------------------------------------------------------------
__global__ void avg_heads(const float* __restrict__ P, float* __restrict__ wavg,
                          int L, int S)
{
    const size_t idx = (size_t)blockIdx.x * 256 + threadIdx.x;
    const size_t LS = (size_t)L * S;
    if (idx >= 2 * LS) return;
    const int b = (int)(idx / LS);
    const size_t rem = idx - (size_t)b * LS;
    float sum = 0.f;
#pragma unroll
    for (int h = 0; h < 8; ++h) sum += P[(size_t)(h * 2 + b) * LS + rem];
    wavg[idx] = sum * 0.125f;
}

// ---------------------------------------------------------------------------
// LayerNorm over rows of 512.
// ---------------------------------------------------------------------------
__global__ __launch_bounds__(256) void ln512(
    const float* __restrict__ X, const float* __restrict__ g,
    const float* __restrict__ be, float* __restrict__ Y)
{
    __shared__ float red[256];
    const int r = blockIdx.x, tid = threadIdx.x;
    const float* xr = X + (size_t)r * 512;
    const float x0 = xr[tid], x1 = xr[tid + 256];
    red[tid] = x0 + x1; __syncthreads();
    for (int st = 128; st; st >>= 1) {
        if (tid < st) red[tid] += red[tid + st];
        __syncthreads();
    }
    const float mean = red[0] * (1.0f / 512.0f); __syncthreads();
    const float d0 = x0 - mean, d1 = x1 - mean;
    red[tid] = d0 * d0 + d1 * d1; __syncthreads();
    for (int st = 128; st; st >>= 1) {
        if (tid < st) red[tid] += red[tid + st];
        __syncthreads();
    }
    const float rstd = rsqrtf(red[0] * (1.0f / 512.0f) + LN_EPS);
    float* yr = Y + (size_t)r * 512;
    yr[tid]       = d0 * rstd * g[tid] + be[tid];
    yr[tid + 256] = d1 * rstd * g[tid + 256] + be[tid + 256];
}

// ---------------------------------------------------------------------------
// Row softmax; out1 may alias X (in-place). Optional second copy out2.
// ---------------------------------------------------------------------------
__global__ __launch_bounds__(256) void softmax_rows(
    const float* __restrict__ X, int S,
    float* __restrict__ out1, float* __restrict__ out2)
{
    __shared__ float sc[2048];
    __shared__ float red[256];
    const int r = blockIdx.x, tid = threadIdx.x;
    const float* xr = X + (size_t)r * S;
    float lmax = -1e30f;
    for (int s = tid; s < S; s += 256) {
        const float v = xr[s]; sc[s] = v; lmax = fmaxf(lmax, v);
    }
    red[tid] = lmax; __syncthreads();
    for (int st = 128; st; st >>= 1) {
        if (tid < st) red[tid] = fmaxf(red[tid], red[tid + st]);
        __syncthreads();
    }
    const float mx = red[0]; __syncthreads();
    float lsum = 0.f;
    for (int s = tid; s < S; s += 256) {
        const float p = __expf(sc[s] - mx); sc[s] = p; lsum += p;
    }
    red[tid] = lsum; __syncthreads();
    for (int st = 128; st; st >>= 1) {
        if (tid < st) red[tid] += red[tid + st];
        __syncthreads();
    }
    const float inv = 1.0f / red[0];
    for (int s = tid; s < S; s += 256) {
        const float p = sc[s] * inv;
        out1[(size_t)r * S + s] = p;
        if (out2) out2[(size_t)r * S + s] = p;
    }
}

// ---------------------------------------------------------------------------
// pair = entire_pair.at[ind_pair].set(sp) realized lazily via inverse map.
// ---------------------------------------------------------------------------
__global__ void init_inv(int* __restrict__ inv) {
    const int i = blockIdx.x * 256 + threadIdx.x;
    if (i < 4096) inv[i] = -1;
}
__global__ void scatter_inv(int* __restrict__ inv, const int* __restrict__ ind, int n) {
    const int i = blockIdx.x * 256 + threadIdx.x;
    if (i < n) inv[ind[i]] = i;
}
__global__ void gather_rows(
    float4* __restrict__ dst, const float4* __restrict__ sp,
    const float4* __restrict__ ep, const int* __restrict__ ind,
    const int* __restrict__ inv, int total4)
{
    const int e = blockIdx.x * 256 + threadIdx.x;
    if (e >= total4) return;
    const int row = e >> 7, c = e & 127;
    const int j = row >> 1, b = row & 1;
    const int idx = ind[j];
    const int iv = inv[idx];
    const float4* src = (iv >= 0) ? (sp + (size_t)(iv * 2 + b) * 128)
                                  : (ep + (size_t)(idx * 2 + b) * 128);
    dst[e] = src[c];
}

// ---------------------------------------------------------------------------
extern "C" void kernel_launch(void* const* d_in, const int* in_sizes, int n_in,
                              void* d_out, int out_size, void* d_ws, size_t ws_size,
                              hipStream_t stream)
{
    (void)in_sizes; (void)n_in; (void)out_size; (void)ws_size;

    const float* in_sp = (const float*)d_in[0];   // (1024,2,512)
    const float* in_su = (const float*)d_in[1];   // (256,2,512)
    const float* in_ep = (const float*)d_in[2];   // (4096,2,512)
    const int* ind_pair = (const int*)d_in[3];
    const int* ind_e2e  = (const int*)d_in[4];
    const int* ind_n2e  = (const int*)d_in[5];
    const float *Wi_sa  = (const float*)d_in[6],  *bi_sa  = (const float*)d_in[7];
    const float *Wo_sa  = (const float*)d_in[8],  *bo_sa  = (const float*)d_in[9];
    const float *Wi_san = (const float*)d_in[10], *bi_san = (const float*)d_in[11];
    const float *Wo_san = (const float*)d_in[12], *bo_san = (const float*)d_in[13];
    const float *Wi_e2e = (const float*)d_in[14], *bi_e2e = (const float*)d_in[15];
    const float *Wo_e2e = (const float*)d_in[16], *bo_e2e = (const float*)d_in[17];
    const float *Wi_n2e = (const float*)d_in[18], *bi_n2e = (const float*)d_in[19];
    const float *Wo_n2e = (const float*)d_in[20], *bo_n2e = (const float*)d_in[21];
    const float *Wi_n2n = (const float*)d_in[22], *bi_n2n = (const float*)d_in[23];
    const float *Wo_n2n = (const float*)d_in[24], *bo_n2n = (const float*)d_in[25];
    const float *W1  = (const float*)d_in[26], *b1f  = (const float*)d_in[27];
    const float *W2  = (const float*)d_in[28], *b2f  = (const float*)d_in[29];
    const float *W1u = (const float*)d_in[30], *b1fu = (const float*)d_in[31];
    const float *W2u = (const float*)d_in[32], *b2fu = (const float*)d_in[33];
    const float *g1  = (const float*)d_in[34], *g1u = (const float*)d_in[35];
    const float *g2  = (const float*)d_in[36], *g3  = (const float*)d_in[37];
    const float *be1 = (const float*)d_in[38], *be1u = (const float*)d_in[39];
    const float *be2 = (const float*)d_in[40], *be3  = (const float*)d_in[41];

    // workspace layout (floats)
    float* W = (float*)d_ws;
    size_t o = 0;
    auto alloc = [&](size_t n) { float* p = W + o; o += n; return p; };
    float* sp    = alloc((size_t)2048 * 512);
    float* su    = alloc((size_t)512 * 512);
    float* ge2e  = alloc((size_t)4096 * 512);
    float* gn2e  = alloc((size_t)4096 * 512);
    float* qkv   = alloc((size_t)2048 * 1536);
    float* kv    = alloc((size_t)4096 * 1024);
    float* att   = alloc((size_t)2048 * 512);
    float* tmp0  = alloc((size_t)2048 * 512);
    float* tmp1  = alloc((size_t)2048 * 512);
    float* ffnh  = alloc((size_t)2048 * 2048);
    float* upn2e = alloc((size_t)512 * 512);
    float* w_e2e = alloc((size_t)2 * 1024 * 2048);
    float* w_n2e = alloc((size_t)2 * 256 * 2048);
    float* w_n2n = alloc((size_t)2 * 256 * 256);
    float* probs = alloc((size_t)16 * 1024 * 2048);   // reused per attention
    int*   inv   = (int*)(W + o);

    float* out_uu = (float*)d_out;                 // updated_unary (256,2,512)
    float* out_up = out_uu + 262144;               // updated_pair (1024,2,512)
    float* out_w1 = out_up + 1048576;              // w_e2e  (2,1024,2048)
    float* out_w2 = out_w1 + 4194304;              // w_e2e again
    float* out_w3 = out_w2 + 4194304;              // w_n2e  (2,256,2048)
    float* out_w4 = out_w3 + 1048576;              // w_n2n  (2,256,256)

    const dim3 blk(256);
    auto gemm = [&](const float* A, const float* B, const float* bias,
                    const float* r1, const float* r2, float scale, bool relu,
                    float* C, int M, int N, int K) {
        dim3 grid(N / 64, M / 64);
        if (relu)
            gemm_nt<true><<<grid, blk, 0, stream>>>(A, B, bias, r1, r2, scale, C, M, N, K);
        else
            gemm_nt<false><<<grid, blk, 0, stream>>>(A, B, bias, r1, r2, scale, C, M, N, K);
    };
    // attention: Q rows (ldq), K/V rows (ldk/ldv), writes att rows of 512;
    // if wavg != nullptr also produces head-averaged probs (2,L,S).
    auto attention = [&](const float* Q, int ldq, const float* Kp, int ldk,
                         const float* Vp, int ldv, float* attout,
                         float* wavg, int L, int S) {
        attn_score<<<dim3(S / 64, L / 64, 16), blk, 0, stream>>>(Q, ldq, Kp, ldk, probs, L, S);
        softmax_rows<<<16 * L, blk, 0, stream>>>(probs, S, probs, nullptr);
        attn_pv<<<dim3(L / 64, 16), blk, 0, stream>>>(probs, Vp, ldv, attout, L, S);
        if (wavg) {
            int total = 2 * L * S;
            avg_heads<<<(total + 255) / 256, blk, 0, stream>>>(probs, wavg, L, S);
        }
    };

    // inverse scatter map for pair assembly
    init_inv<<<16, blk, 0, stream>>>(inv);
    scatter_inv<<<4, blk, 0, stream>>>(inv, ind_pair, 1024);

    // ---- self-attention on sparsified_pair -> sp
    gemm(in_sp, Wi_sa, bi_sa, nullptr, nullptr, 1.f, false, qkv, 2048, 1536, 512);
    attention(qkv, 1536, qkv + 512, 1536, qkv + 1024, 1536, att, nullptr, 1024, 1024);
    gemm(att, Wo_sa, bo_sa, in_sp, nullptr, 1.f, false, tmp0, 2048, 512, 512);
    ln512<<<2048, blk, 0, stream>>>(tmp0, g1, be1, sp);

    // ---- self-attention on sparsified_unary -> su
    gemm(in_su, Wi_san, bi_san, nullptr, nullptr, 1.f, false, qkv, 512, 1536, 512);
    attention(qkv, 1536, qkv + 512, 1536, qkv + 1024, 1536, att, nullptr, 256, 256);
    gemm(att, Wo_san, bo_san, in_su, nullptr, 1.f, false, tmp0, 512, 512, 512);
    ln512<<<512, blk, 0, stream>>>(tmp0, g1u, be1u, su);

    // ---- gathers: pair_e2e, pair_n2e
    gather_rows<<<2048, blk, 0, stream>>>((float4*)ge2e, (const float4*)sp,
                                          (const float4*)in_ep, ind_e2e, inv, 524288);
    gather_rows<<<2048, blk, 0, stream>>>((float4*)gn2e, (const float4*)sp,
                                          (const float4*)in_ep, ind_n2e, inv, 524288);

    // ---- e2e cross-attention: q=sp, kv=pair_e2e
    gemm(sp, Wi_e2e, bi_e2e, nullptr, nullptr, 1.f, false, qkv, 2048, 512, 512);
    gemm(ge2e, Wi_e2e + 512 * 512, bi_e2e + 512, nullptr, nullptr, 1.f, false, kv, 4096, 1024, 512);
    attention(qkv, 512, kv, 1024, kv + 512, 1024, att, w_e2e, 1024, 2048);
    gemm(att, Wo_e2e, bo_e2e, sp, nullptr, 2.f, false, tmp0, 2048, 512, 512);  // sp + 2*up_e2e
    ln512<<<2048, blk, 0, stream>>>(tmp0, g2, be2, tmp1);
    // FFN (pair)
    gemm(tmp1, W1, b1f, nullptr, nullptr, 1.f, true, ffnh, 2048, 2048, 512);
    gemm(ffnh, W2, b2f, tmp1, nullptr, 1.f, false, tmp0, 2048, 512, 2048);
    ln512<<<2048, blk, 0, stream>>>(tmp0, g3, be3, out_up);

    // ---- n2e cross-attention: q=su, kv=pair_n2e
    gemm(su, Wi_n2e, bi_n2e, nullptr, nullptr, 1.f, false, qkv, 512, 512, 512);
    gemm(gn2e, Wi_n2e + 512 * 512, bi_n2e + 512, nullptr, nullptr, 1.f, false, kv, 4096, 1024, 512);
    attention(qkv, 512, kv, 1024, kv + 512, 1024, att, w_n2e, 256, 2048);
    gemm(att, Wo_n2e, bo_n2e, nullptr, nullptr, 1.f, false, upn2e, 512, 512, 512);

    // ---- n2n self-attention on su
    gemm(su, Wi_n2n, bi_n2n, nullptr, nullptr, 1.f, false, qkv, 512, 1536, 512);
    attention(qkv, 1536, qkv + 512, 1536, qkv + 1024, 1536, att, w_n2n, 256, 256);
    gemm(att, Wo_n2n, bo_n2n, su, upn2e, 1.f, false, tmp0, 512, 512, 512); // su+up_n2e+up_n2n
    ln512<<<512, blk, 0, stream>>>(tmp0, g2, be2, tmp1);
    // FFN (unary)
    gemm(tmp1, W1u, b1fu, nullptr, nullptr, 1.f, true, ffnh, 512, 2048, 512);
    gemm(ffnh, W2u, b2fu, tmp1, nullptr, 1.f, false, tmp0, 512, 512, 2048);
    ln512<<<512, blk, 0, stream>>>(tmp0, g3, be3, out_uu);

    // ---- second softmax on averaged weights -> outputs
    softmax_rows<<<2048, blk, 0, stream>>>(w_e2e, 2048, out_w1, out_w2);
    softmax_rows<<<512, blk, 0, stream>>>(w_n2e, 2048, out_w3, nullptr);
    softmax_rows<<<512, blk, 0, stream>>>(w_n2n, 256, out_w4, nullptr);
}

// Round 3
// 1019.546 us; speedup vs baseline: 6.4841x; 1.7563x over previous
//
#include <hip/hip_runtime.h>
#include <cstddef>

#define LN_EPS 1e-5f

typedef unsigned short u16;
typedef short short8 __attribute__((ext_vector_type(8)));
typedef float f32x4 __attribute__((ext_vector_type(4)));

__device__ __forceinline__ u16 f2bf(float f) {
    unsigned int u = __float_as_uint(f);
    u = (u + 0x7FFFu + ((u >> 16) & 1u)) >> 16;
    return (u16)u;
}
__device__ __forceinline__ float bf2f(u16 h) {
    return __uint_as_float((unsigned int)h << 16);
}

// ---------------------------------------------------------------------------
// Multi-tensor fp32 -> bf16 convert (weights + inputs), one launch.
// ---------------------------------------------------------------------------
struct CvtDesc {
    const float* src[16];
    u16* dst[16];
    int n4[16];          // element count / 4
};
__global__ __launch_bounds__(256) void cvt_multi(CvtDesc d) {
    const int t = blockIdx.x * 256 + threadIdx.x;
    const int i = blockIdx.y;
    if (t >= d.n4[i]) return;
    const float4 v = ((const float4*)d.src[i])[t];
    ushort4 o;
    o.x = f2bf(v.x); o.y = f2bf(v.y); o.z = f2bf(v.z); o.w = f2bf(v.w);
    ((ushort4*)d.dst[i])[t] = o;
}

// ---------------------------------------------------------------------------
// bf16 MFMA NT GEMM, 128x128 tile, 4 waves, BK=32, 16x16x32 MFMA.
// C = scale*(A@B^T + bias) + res1 + res2 (+relu). Outputs fp32 and/or bf16.
// Batched over grid.z with bz -> (b = bz&1, h = bz>>1) offsets for A/B/C.
// A[row][k] at A + bOffsets + row*lda + k   (bf16, 16B-aligned rows)
// ---------------------------------------------------------------------------
template<int BM, int BN>
__global__ __launch_bounds__(256) void mfma_gemm(
    const u16* __restrict__ A, int lda, int aOffB, int aOffH,
    const u16* __restrict__ B, int ldb, int bOffB, int bOffH,
    float* __restrict__ Cf, u16* __restrict__ Ch,
    int ldc, long cOffB, long cOffH,
    const float* __restrict__ bias,
    const float* __restrict__ res1, const float* __restrict__ res2,
    float scale, int relu, int K)
{
    constexpr int MF = BM / 32;   // frags per wave in M (wave tile BM/2)
    constexpr int NF = BN / 32;
    __shared__ u16 As[BM * 32];
    __shared__ u16 Bs[BN * 32];

    const int tid = threadIdx.x;
    const int wave = tid >> 6, lane = tid & 63;
    const int wm = wave >> 1, wn = wave & 1;
    const int m0 = blockIdx.y * BM, n0 = blockIdx.x * BN;
    const int bz = blockIdx.z, bb = bz & 1, hh = bz >> 1;
    const size_t aOff = (size_t)bb * aOffB + (size_t)hh * aOffH;
    const size_t bOff = (size_t)bb * bOffB + (size_t)hh * bOffH;
    const size_t cOff = (size_t)bb * cOffB + (size_t)hh * cOffH;

    f32x4 acc[MF][NF];
#pragma unroll
    for (int mf = 0; mf < MF; ++mf)
#pragma unroll
        for (int nf = 0; nf < NF; ++nf) acc[mf][nf] = (f32x4){0.f, 0.f, 0.f, 0.f};

    const int ar = tid >> 2, ac = (tid & 3) * 8;   // 4 threads per 32-elem row
    const int ml = lane & 15, kq = lane >> 4;

    for (int k0 = 0; k0 < K; k0 += 32) {
        __syncthreads();
#pragma unroll
        for (int c = 0; c < BM / 64; ++c) {
            const int r = ar + c * 64;
            *(short8*)&As[r * 32 + ac] =
                *(const short8*)&A[aOff + (size_t)(m0 + r) * lda + k0 + ac];
        }
#pragma unroll
        for (int c = 0; c < BN / 64; ++c) {
            const int r = ar + c * 64;
            *(short8*)&Bs[r * 32 + ac] =
                *(const short8*)&B[bOff + (size_t)(n0 + r) * ldb + k0 + ac];
        }
        __syncthreads();

        short8 af[MF], bfr[NF];
#pragma unroll
        for (int mf = 0; mf < MF; ++mf)
            af[mf] = *(const short8*)&As[(wm * (BM / 2) + mf * 16 + ml) * 32 + kq * 8];
#pragma unroll
        for (int nf = 0; nf < NF; ++nf)
            bfr[nf] = *(const short8*)&Bs[(wn * (BN / 2) + nf * 16 + ml) * 32 + kq * 8];
#pragma unroll
        for (int mf = 0; mf < MF; ++mf)
#pragma unroll
            for (int nf = 0; nf < NF; ++nf)
                acc[mf][nf] = __builtin_amdgcn_mfma_f32_16x16x32_bf16(
                    af[mf], bfr[nf], acc[mf][nf], 0, 0, 0);
    }

    // epilogue: C/D layout col=lane&15, row=(lane>>4)*4+reg
    const int rq = lane >> 4;
#pragma unroll
    for (int mf = 0; mf < MF; ++mf)
#pragma unroll
        for (int nf = 0; nf < NF; ++nf) {
            const int col = n0 + wn * (BN / 2) + nf * 16 + ml;
            const float bv = bias ? bias[col] : 0.f;
#pragma unroll
            for (int r = 0; r < 4; ++r) {
                const int row = m0 + wm * (BM / 2) + mf * 16 + rq * 4 + r;
                float v = scale * (acc[mf][nf][r] + bv);
                const size_t idx = cOff + (size_t)row * ldc + col;
                if (res1) v += res1[idx];
                if (res2) v += res2[idx];
                if (relu) v = fmaxf(v, 0.f);
                if (Cf) Cf[idx] = v;
                if (Ch) Ch[idx] = f2bf(v);
            }
        }
}

// ---------------------------------------------------------------------------
// P @ V per (b,h): out rows (i*2+b)*512 + h*64 + d (bf16).
// P: [bh][L][S] bf16 contiguous.  V: rows (s*2+b)*ldv + h*64 (bf16).
// Tile 128(i) x 64(d), BK=32 over S. 4 waves: 2(m) x 2(n), wave tile 64x32.
// ---------------------------------------------------------------------------
__global__ __launch_bounds__(256) void mfma_pv(
    const u16* __restrict__ P,
    const u16* __restrict__ V, int ldv,
    u16* __restrict__ att, int L, int S)
{
    constexpr int MF = 4, NF = 2;
    __shared__ u16 Ps[128 * 32];
    __shared__ u16 Vs[32 * 64];   // [k][d] natural layout

    const int tid = threadIdx.x;
    const int wave = tid >> 6, lane = tid & 63;
    const int wm = wave >> 1, wn = wave & 1;
    const int i0 = blockIdx.x * 128;
    const int bz = blockIdx.y, bb = bz & 1, hh = bz >> 1;
    const u16* Pb = P + (size_t)bz * L * S;

    const int ar = tid >> 2, ac = (tid & 3) * 8;
    const int vk = tid >> 3, vd = (tid & 7) * 8;
    const int ml = lane & 15, kq = lane >> 4;

    f32x4 acc[MF][NF];
#pragma unroll
    for (int mf = 0; mf < MF; ++mf)
#pragma unroll
        for (int nf = 0; nf < NF; ++nf) acc[mf][nf] = (f32x4){0.f, 0.f, 0.f, 0.f};

    for (int k0 = 0; k0 < S; k0 += 32) {
        __syncthreads();
#pragma unroll
        for (int c = 0; c < 2; ++c) {
            const int r = ar + c * 64;
            *(short8*)&Ps[r * 32 + ac] =
                *(const short8*)&Pb[(size_t)(i0 + r) * S + k0 + ac];
        }
        *(short8*)&Vs[vk * 64 + vd] =
            *(const short8*)&V[(size_t)((k0 + vk) * 2 + bb) * ldv + hh * 64 + vd];
        __syncthreads();

        short8 af[MF], bfr[NF];
#pragma unroll
        for (int mf = 0; mf < MF; ++mf)
            af[mf] = *(const short8*)&Ps[(wm * 64 + mf * 16 + ml) * 32 + kq * 8];
#pragma unroll
        for (int nf = 0; nf < NF; ++nf) {
            const int n = wn * 32 + nf * 16 + ml;
#pragma unroll
            for (int j = 0; j < 8; ++j)
                bfr[nf][j] = (short)Vs[(kq * 8 + j) * 64 + n];
        }
#pragma unroll
        for (int mf = 0; mf < MF; ++mf)
#pragma unroll
            for (int nf = 0; nf < NF; ++nf)
                acc[mf][nf] = __builtin_amdgcn_mfma_f32_16x16x32_bf16(
                    af[mf], bfr[nf], acc[mf][nf], 0, 0, 0);
    }

    const int rq = lane >> 4;
#pragma unroll
    for (int mf = 0; mf < MF; ++mf)
#pragma unroll
        for (int nf = 0; nf < NF; ++nf) {
            const int d = wn * 32 + nf * 16 + ml;
#pragma unroll
            for (int r = 0; r < 4; ++r) {
                const int i = i0 + wm * 64 + mf * 16 + rq * 4 + r;
                att[((size_t)i * 2 + bb) * 512 + hh * 64 + d] = f2bf(acc[mf][nf][r]);
            }
        }
}

// ---------------------------------------------------------------------------
// In-place row softmax on bf16 rows (scores -> probs). grid = nRows.
// ---------------------------------------------------------------------------
__global__ __launch_bounds__(256) void softmax_bf(u16* __restrict__ X, int S) {
    __shared__ float sc[2048];
    __shared__ float red[256];
    const int tid = threadIdx.x;
    u16* xr = X + (size_t)blockIdx.x * S;
    float lmax = -1e30f;
    for (int s = tid; s < S; s += 256) {
        const float v = bf2f(xr[s]); sc[s] = v; lmax = fmaxf(lmax, v);
    }
    red[tid] = lmax; __syncthreads();
    for (int st = 128; st; st >>= 1) {
        if (tid < st) red[tid] = fmaxf(red[tid], red[tid + st]);
        __syncthreads();
    }
    const float mx = red[0]; __syncthreads();
    float lsum = 0.f;
    for (int s = tid; s < S; s += 256) {
        const float p = __expf(sc[s] - mx); sc[s] = p; lsum += p;
    }
    red[tid] = lsum; __syncthreads();
    for (int st = 128; st; st >>= 1) {
        if (tid < st) red[tid] += red[tid + st];
        __syncthreads();
    }
    const float inv = 1.0f / red[0];
    for (int s = tid; s < S; s += 256) xr[s] = f2bf(sc[s] * inv);
}

// ---------------------------------------------------------------------------
// Head-average of bf16 probs + second softmax -> fp32 out (1 or 2 copies).
// grid = 2*L, blockIdx.x = b*L + i.
// ---------------------------------------------------------------------------
__global__ __launch_bounds__(256) void avg_softmax(
    const u16* __restrict__ P, int L, int S,
    float* __restrict__ out1, float* __restrict__ out2)
{
    __shared__ float wacc[2048];
    __shared__ float red[256];
    const int tid = threadIdx.x;
    const int b = blockIdx.x / L, i = blockIdx.x % L;
    const size_t LS = (size_t)L * S;

    for (int s = tid; s < S; s += 256) {
        float sum = 0.f;
#pragma unroll
        for (int h = 0; h < 8; ++h)
            sum += bf2f(P[(size_t)(h * 2 + b) * LS + (size_t)i * S + s]);
        wacc[s] = sum * 0.125f;
    }
    __syncthreads();
    float lmax = -1e30f;
    for (int s = tid; s < S; s += 256) lmax = fmaxf(lmax, wacc[s]);
    red[tid] = lmax; __syncthreads();
    for (int st = 128; st; st >>= 1) {
        if (tid < st) red[tid] = fmaxf(red[tid], red[tid + st]);
        __syncthreads();
    }
    const float mx = red[0]; __syncthreads();
    float lsum = 0.f;
    for (int s = tid; s < S; s += 256) {
        const float p = __expf(wacc[s] - mx); wacc[s] = p; lsum += p;
    }
    red[tid] = lsum; __syncthreads();
    for (int st = 128; st; st >>= 1) {
        if (tid < st) red[tid] += red[tid + st];
        __syncthreads();
    }
    const float inv = 1.0f / red[0];
    const size_t rbase = (size_t)blockIdx.x * S;
    for (int s = tid; s < S; s += 256) {
        const float p = wacc[s] * inv;
        out1[rbase + s] = p;
        if (out2) out2[rbase + s] = p;
    }
}

// ---------------------------------------------------------------------------
// LayerNorm over rows of 512; fp32 out + optional bf16 out.
// ---------------------------------------------------------------------------
__global__ __launch_bounds__(256) void ln512(
    const float* __restrict__ X, const float* __restrict__ g,
    const float* __restrict__ be, float* __restrict__ Yf, u16* __restrict__ Yb)
{
    __shared__ float red[256];
    const int r = blockIdx.x, tid = threadIdx.x;
    const float* xr = X + (size_t)r * 512;
    const float x0 = xr[tid], x1 = xr[tid + 256];
    red[tid] = x0 + x1; __syncthreads();
    for (int st = 128; st; st >>= 1) {
        if (tid < st) red[tid] += red[tid + st];
        __syncthreads();
    }
    const float mean = red[0] * (1.0f / 512.0f); __syncthreads();
    const float d0 = x0 - mean, d1 = x1 - mean;
    red[tid] = d0 * d0 + d1 * d1; __syncthreads();
    for (int st = 128; st; st >>= 1) {
        if (tid < st) red[tid] += red[tid + st];
        __syncthreads();
    }
    const float rstd = rsqrtf(red[0] * (1.0f / 512.0f) + LN_EPS);
    const float y0 = d0 * rstd * g[tid] + be[tid];
    const float y1 = d1 * rstd * g[tid + 256] + be[tid + 256];
    float* yr = Yf + (size_t)r * 512;
    yr[tid] = y0; yr[tid + 256] = y1;
    if (Yb) {
        u16* yb = Yb + (size_t)r * 512;
        yb[tid] = f2bf(y0); yb[tid + 256] = f2bf(y1);
    }
}

// ---------------------------------------------------------------------------
// pair assembly: inverse map + gather rows to bf16.
// ---------------------------------------------------------------------------
__global__ void init_inv(int* __restrict__ inv) {
    const int i = blockIdx.x * 256 + threadIdx.x;
    if (i < 4096) inv[i] = -1;
}
__global__ void scatter_inv(int* __restrict__ inv, const int* __restrict__ ind, int n) {
    const int i = blockIdx.x * 256 + threadIdx.x;
    if (i < n) inv[ind[i]] = i;
}
// dst rows (j*2+b) of 512 bf16 <- (inv[ind[j]]>=0 ? spf : entire_pair)
__global__ void gather_rows_bf(
    u16* __restrict__ dst, const float* __restrict__ spf,
    const float* __restrict__ ep, const int* __restrict__ ind,
    const int* __restrict__ inv, int total4)
{
    const int e = blockIdx.x * 256 + threadIdx.x;
    if (e >= total4) return;
    const int row = e >> 7, c = e & 127;          // 128 float4 per row
    const int j = row >> 1, b = row & 1;
    const int idx = ind[j];
    const int iv = inv[idx];
    const float4* src = (iv >= 0) ? (const float4*)(spf + (size_t)(iv * 2 + b) * 512)
                                  : (const float4*)(ep + (size_t)(idx * 2 + b) * 512);
    const float4 v = src[c];
    ushort4 o; o.x = f2bf(v.x); o.y = f2bf(v.y); o.z = f2bf(v.z); o.w = f2bf(v.w);
    ((ushort4*)dst)[e] = o;
}

// ---------------------------------------------------------------------------
extern "C" void kernel_launch(void* const* d_in, const int* in_sizes, int n_in,
                              void* d_out, int out_size, void* d_ws, size_t ws_size,
                              hipStream_t stream)
{
    (void)in_sizes; (void)n_in; (void)out_size; (void)ws_size;

    const float* in_sp = (const float*)d_in[0];
    const float* in_su = (const float*)d_in[1];
    const float* in_ep = (const float*)d_in[2];
    const int* ind_pair = (const int*)d_in[3];
    const int* ind_e2e  = (const int*)d_in[4];
    const int* ind_n2e  = (const int*)d_in[5];
    const float *Wi_sa  = (const float*)d_in[6],  *bi_sa  = (const float*)d_in[7];
    const float *Wo_sa  = (const float*)d_in[8],  *bo_sa  = (const float*)d_in[9];
    const float *Wi_san = (const float*)d_in[10], *bi_san = (const float*)d_in[11];
    const float *Wo_san = (const float*)d_in[12], *bo_san = (const float*)d_in[13];
    const float *Wi_e2e = (const float*)d_in[14], *bi_e2e = (const float*)d_in[15];
    const float *Wo_e2e = (const float*)d_in[16], *bo_e2e = (const float*)d_in[17];
    const float *Wi_n2e = (const float*)d_in[18], *bi_n2e = (const float*)d_in[19];
    const float *Wo_n2e = (const float*)d_in[20], *bo_n2e = (const float*)d_in[21];
    const float *Wi_n2n = (const float*)d_in[22], *bi_n2n = (const float*)d_in[23];
    const float *Wo_n2n = (const float*)d_in[24], *bo_n2n = (const float*)d_in[25];
    const float *W1  = (const float*)d_in[26], *b1f  = (const float*)d_in[27];
    const float *W2  = (const float*)d_in[28], *b2f  = (const float*)d_in[29];
    const float *W1u = (const float*)d_in[30], *b1fu = (const float*)d_in[31];
    const float *W2u = (const float*)d_in[32], *b2fu = (const float*)d_in[33];
    const float *g1  = (const float*)d_in[34], *g1u = (const float*)d_in[35];
    const float *g2  = (const float*)d_in[36], *g3  = (const float*)d_in[37];
    const float *be1 = (const float*)d_in[38], *be1u = (const float*)d_in[39];
    const float *be2 = (const float*)d_in[40], *be3  = (const float*)d_in[41];

    // ---- workspace: fp32 region then bf16(u16) region
    float* Wf = (float*)d_ws;
    size_t of = 0;
    auto af_ = [&](size_t n) { float* p = Wf + of; of += n; return p; };
    float* spf    = af_((size_t)2048 * 512);
    float* suf    = af_((size_t)512 * 512);
    float* tmp0f  = af_((size_t)2048 * 512);
    float* tmp1f  = af_((size_t)2048 * 512);
    float* upn2ef = af_((size_t)512 * 512);

    u16* Wu = (u16*)(Wf + of);
    size_t ou = 0;
    auto au_ = [&](size_t n) { u16* p = Wu + ou; ou += n; return p; };
    u16* in_spb = au_((size_t)2048 * 512);
    u16* in_sub = au_((size_t)512 * 512);
    u16* spb    = au_((size_t)2048 * 512);
    u16* sub    = au_((size_t)512 * 512);
    u16* ge2eb  = au_((size_t)4096 * 512);
    u16* gn2eb  = au_((size_t)4096 * 512);
    u16* qkvb   = au_((size_t)2048 * 1536);
    u16* kvb    = au_((size_t)4096 * 1024);
    u16* attb   = au_((size_t)2048 * 512);
    u16* tmp1b  = au_((size_t)2048 * 512);
    u16* ffnb   = au_((size_t)2048 * 2048);
    u16* probs  = au_((size_t)16 * 1024 * 2048);
    u16* wb[14];
    const int wsz[14] = {786432, 262144, 786432, 262144, 786432, 262144, 786432,
                         262144, 786432, 262144, 1048576, 1048576, 1048576, 1048576};
    for (int i = 0; i < 14; ++i) wb[i] = au_((size_t)wsz[i]);
    int* inv = (int*)(Wu + ou);

    float* out_uu = (float*)d_out;
    float* out_up = out_uu + 262144;
    float* out_w1 = out_up + 1048576;
    float* out_w2 = out_w1 + 4194304;
    float* out_w3 = out_w2 + 4194304;
    float* out_w4 = out_w3 + 1048576;

    const dim3 blk(256);

    // ---- one-shot conversions
    CvtDesc cd;
    const float* wsrc[14] = {Wi_sa, Wo_sa, Wi_san, Wo_san, Wi_e2e, Wo_e2e, Wi_n2e,
                             Wo_n2e, Wi_n2n, Wo_n2n, W1, W2, W1u, W2u};
    for (int i = 0; i < 14; ++i) { cd.src[i] = wsrc[i]; cd.dst[i] = wb[i]; cd.n4[i] = wsz[i] / 4; }
    cd.src[14] = in_sp; cd.dst[14] = in_spb; cd.n4[14] = 1048576 / 4;
    cd.src[15] = in_su; cd.dst[15] = in_sub; cd.n4[15] = 262144 / 4;
    cvt_multi<<<dim3(1024, 16), blk, 0, stream>>>(cd);

    init_inv<<<16, blk, 0, stream>>>(inv);
    scatter_inv<<<4, blk, 0, stream>>>(inv, ind_pair, 1024);

    auto gemm = [&](const u16* A, int lda, int aOffB, int aOffH,
                    const u16* B, int ldb, int bOffB, int bOffH,
                    float* Cf, u16* Ch, int ldc, long cOffB, long cOffH,
                    const float* bias, const float* r1, const float* r2,
                    float scale, int relu, int M, int N, int K, int batch) {
        mfma_gemm<128, 128><<<dim3(N / 128, M / 128, batch), blk, 0, stream>>>(
            A, lda, aOffB, aOffH, B, ldb, bOffB, bOffH, Cf, Ch, ldc, cOffB, cOffH,
            bias, r1, r2, scale, relu, K);
    };

    // ================= self-attention (pair) =================
    gemm(in_spb, 512, 0, 0, wb[0], 512, 0, 0, nullptr, qkvb, 1536, 0, 0,
         bi_sa, nullptr, nullptr, 1.f, 0, 2048, 1536, 512, 1);
    gemm(qkvb, 3072, 1536, 64, qkvb + 512, 3072, 1536, 64, nullptr, probs,
         1024, 1048576L, 2097152L, nullptr, nullptr, nullptr, 0.125f, 0, 1024, 1024, 64, 16);
    softmax_bf<<<16384, blk, 0, stream>>>(probs, 1024);
    mfma_pv<<<dim3(8, 16), blk, 0, stream>>>(probs, qkvb + 1024, 1536, attb, 1024, 1024);
    gemm(attb, 512, 0, 0, wb[1], 512, 0, 0, tmp0f, nullptr, 512, 0, 0,
         bo_sa, in_sp, nullptr, 1.f, 0, 2048, 512, 512, 1);
    ln512<<<2048, blk, 0, stream>>>(tmp0f, g1, be1, spf, spb);

    // ================= self-attention (unary) =================
    gemm(in_sub, 512, 0, 0, wb[2], 512, 0, 0, nullptr, qkvb, 1536, 0, 0,
         bi_san, nullptr, nullptr, 1.f, 0, 512, 1536, 512, 1);
    gemm(qkvb, 3072, 1536, 64, qkvb + 512, 3072, 1536, 64, nullptr, probs,
         256, 65536L, 131072L, nullptr, nullptr, nullptr, 0.125f, 0, 256, 256, 64, 16);
    softmax_bf<<<4096, blk, 0, stream>>>(probs, 256);
    mfma_pv<<<dim3(2, 16), blk, 0, stream>>>(probs, qkvb + 1024, 1536, attb, 256, 256);
    gemm(attb, 512, 0, 0, wb[3], 512, 0, 0, tmp0f, nullptr, 512, 0, 0,
         bo_san, in_su, nullptr, 1.f, 0, 512, 512, 512, 1);
    ln512<<<512, blk, 0, stream>>>(tmp0f, g1u, be1u, suf, sub);

    // ================= gathers =================
    gather_rows_bf<<<2048, blk, 0, stream>>>(ge2eb, spf, in_ep, ind_e2e, inv, 524288);
    gather_rows_bf<<<2048, blk, 0, stream>>>(gn2eb, spf, in_ep, ind_n2e, inv, 524288);

    // ================= e2e cross-attention =================
    gemm(spb, 512, 0, 0, wb[4], 512, 0, 0, nullptr, qkvb, 512, 0, 0,
         bi_e2e, nullptr, nullptr, 1.f, 0, 2048, 512, 512, 1);
    gemm(ge2eb, 512, 0, 0, wb[4] + 262144, 512, 0, 0, nullptr, kvb, 1024, 0, 0,
         bi_e2e + 512, nullptr, nullptr, 1.f, 0, 4096, 1024, 512, 1);
    gemm(qkvb, 1024, 512, 64, kvb, 2048, 1024, 64, nullptr, probs,
         2048, 2097152L, 4194304L, nullptr, nullptr, nullptr, 0.125f, 0, 1024, 2048, 64, 16);
    softmax_bf<<<16384, blk, 0, stream>>>(probs, 2048);
    mfma_pv<<<dim3(8, 16), blk, 0, stream>>>(probs, kvb + 512, 1024, attb, 1024, 2048);
    avg_softmax<<<2048, blk, 0, stream>>>(probs, 1024, 2048, out_w1, out_w2);
    gemm(attb, 512, 0, 0, wb[5], 512, 0, 0, tmp0f, nullptr, 512, 0, 0,
         bo_e2e, spf, nullptr, 2.f, 0, 2048, 512, 512, 1);
    ln512<<<2048, blk, 0, stream>>>(tmp0f, g2, be2, tmp1f, tmp1b);
    // FFN (pair)
    gemm(tmp1b, 512, 0, 0, wb[10], 512, 0, 0, nullptr, ffnb, 2048, 0, 0,
         b1f, nullptr, nullptr, 1.f, 1, 2048, 2048, 512, 1);
    gemm(ffnb, 2048, 0, 0, wb[11], 2048, 0, 0, tmp0f, nullptr, 512, 0, 0,
         b2f, tmp1f, nullptr, 1.f, 0, 2048, 512, 2048, 1);
    ln512<<<2048, blk, 0, stream>>>(tmp0f, g3, be3, out_up, nullptr);

    // ================= n2e cross-attention =================
    gemm(sub, 512, 0, 0, wb[6], 512, 0, 0, nullptr, qkvb, 512, 0, 0,
         bi_n2e, nullptr, nullptr, 1.f, 0, 512, 512, 512, 1);
    gemm(gn2eb, 512, 0, 0, wb[6] + 262144, 512, 0, 0, nullptr, kvb, 1024, 0, 0,
         bi_n2e + 512, nullptr, nullptr, 1.f, 0, 4096, 1024, 512, 1);
    gemm(qkvb, 1024, 512, 64, kvb, 2048, 1024, 64, nullptr, probs,
         2048, 524288L, 1048576L, nullptr, nullptr, nullptr, 0.125f, 0, 256, 2048, 64, 16);
    softmax_bf<<<4096, blk, 0, stream>>>(probs, 2048);
    mfma_pv<<<dim3(2, 16), blk, 0, stream>>>(probs, kvb + 512, 1024, attb, 256, 2048);
    avg_softmax<<<512, blk, 0, stream>>>(probs, 256, 2048, out_w3, nullptr);
    gemm(attb, 512, 0, 0, wb[7], 512, 0, 0, upn2ef, nullptr, 512, 0, 0,
         bo_n2e, nullptr, nullptr, 1.f, 0, 512, 512, 512, 1);

    // ================= n2n self-attention =================
    gemm(sub, 512, 0, 0, wb[8], 512, 0, 0, nullptr, qkvb, 1536, 0, 0,
         bi_n2n, nullptr, nullptr, 1.f, 0, 512, 1536, 512, 1);
    gemm(qkvb, 3072, 1536, 64, qkvb + 512, 3072, 1536, 64, nullptr, probs,
         256, 65536L, 131072L, nullptr, nullptr, nullptr, 0.125f, 0, 256, 256, 64, 16);
    softmax_bf<<<4096, blk, 0, stream>>>(probs, 256);
    mfma_pv<<<dim3(2, 16), blk, 0, stream>>>(probs, qkvb + 1024, 1536, attb, 256, 256);
    avg_softmax<<<512, blk, 0, stream>>>(probs, 256, 256, out_w4, nullptr);
    gemm(attb, 512, 0, 0, wb[9], 512, 0, 0, tmp0f, nullptr, 512, 0, 0,
         bo_n2n, suf, upn2ef, 1.f, 0, 512, 512, 512, 1);
    ln512<<<512, blk, 0, stream>>>(tmp0f, g2, be2, tmp1f, tmp1b);
    // FFN (unary)
    gemm(tmp1b, 512, 0, 0, wb[12], 512, 0, 0, nullptr, ffnb, 2048, 0, 0,
         b1fu, nullptr, nullptr, 1.f, 1, 512, 2048, 512, 1);
    gemm(ffnb, 2048, 0, 0, wb[13], 2048, 0, 0, tmp0f, nullptr, 512, 0, 0,
         b2fu, tmp1f, nullptr, 1.f, 0, 512, 512, 2048, 1);
    ln512<<<512, blk, 0, stream>>>(tmp0f, g3, be3, out_uu, nullptr);
}

// Round 4
// 815.070 us; speedup vs baseline: 8.1108x; 1.2509x over previous
//
#include <hip/hip_runtime.h>
#include <cstddef>

#define LN_EPS 1e-5f

typedef unsigned short u16;
typedef short short8 __attribute__((ext_vector_type(8)));
typedef float f32x4 __attribute__((ext_vector_type(4)));

__device__ __forceinline__ u16 f2bf(float f) {
    unsigned int u = __float_as_uint(f);
    u = (u + 0x7FFFu + ((u >> 16) & 1u)) >> 16;
    return (u16)u;
}
__device__ __forceinline__ float bf2f(u16 h) {
    return __uint_as_float((unsigned int)h << 16);
}

// ---------------------------------------------------------------------------
// Multi-tensor fp32 -> bf16 convert (weights + inputs), one launch.
// ---------------------------------------------------------------------------
struct CvtDesc {
    const float* src[16];
    u16* dst[16];
    int n4[16];
};
__global__ __launch_bounds__(256) void cvt_multi(CvtDesc d) {
    const int t = blockIdx.x * 256 + threadIdx.x;
    const int i = blockIdx.y;
    if (t >= d.n4[i]) return;
    const float4 v = ((const float4*)d.src[i])[t];
    ushort4 o;
    o.x = f2bf(v.x); o.y = f2bf(v.y); o.z = f2bf(v.z); o.w = f2bf(v.w);
    ((ushort4*)d.dst[i])[t] = o;
}

// ---------------------------------------------------------------------------
// bf16 MFMA NT GEMM, BMxBN tile, 4 waves (2x2), BK=32, 16x16x32 MFMA.
// C = scale*(A@B^T + bias) + res1 + res2 (+relu). Outputs fp32 and/or bf16.
// Batched over grid.z: bz -> (b = bz&1, h = bz>>1) offsets for A/B/C.
// BM=BN=64 for skinny shapes (grid >= ~256 blocks), 128 for big shapes.
// ---------------------------------------------------------------------------
template<int BM, int BN>
__global__ __launch_bounds__(256) void mfma_gemm(
    const u16* __restrict__ A, int lda, int aOffB, int aOffH,
    const u16* __restrict__ B, int ldb, int bOffB, int bOffH,
    float* __restrict__ Cf, u16* __restrict__ Ch,
    int ldc, long cOffB, long cOffH,
    const float* __restrict__ bias,
    const float* __restrict__ res1, const float* __restrict__ res2,
    float scale, int relu, int K)
{
    constexpr int MF = BM / 32;
    constexpr int NF = BN / 32;
    __shared__ u16 As[BM * 32];
    __shared__ u16 Bs[BN * 32];

    const int tid = threadIdx.x;
    const int wave = tid >> 6, lane = tid & 63;
    const int wm = wave >> 1, wn = wave & 1;
    const int m0 = blockIdx.y * BM, n0 = blockIdx.x * BN;
    const int bz = blockIdx.z, bb = bz & 1, hh = bz >> 1;
    const size_t aOff = (size_t)bb * aOffB + (size_t)hh * aOffH;
    const size_t bOff = (size_t)bb * bOffB + (size_t)hh * bOffH;
    const size_t cOff = (size_t)bb * cOffB + (size_t)hh * cOffH;

    f32x4 acc[MF][NF];
#pragma unroll
    for (int mf = 0; mf < MF; ++mf)
#pragma unroll
        for (int nf = 0; nf < NF; ++nf) acc[mf][nf] = (f32x4){0.f, 0.f, 0.f, 0.f};

    const int ar = tid >> 2, ac = (tid & 3) * 8;
    const int ml = lane & 15, kq = lane >> 4;

    for (int k0 = 0; k0 < K; k0 += 32) {
        __syncthreads();
#pragma unroll
        for (int c = 0; c < BM / 64; ++c) {
            const int r = ar + c * 64;
            *(short8*)&As[r * 32 + ac] =
                *(const short8*)&A[aOff + (size_t)(m0 + r) * lda + k0 + ac];
        }
#pragma unroll
        for (int c = 0; c < BN / 64; ++c) {
            const int r = ar + c * 64;
            *(short8*)&Bs[r * 32 + ac] =
                *(const short8*)&B[bOff + (size_t)(n0 + r) * ldb + k0 + ac];
        }
        __syncthreads();

        short8 af[MF], bfr[NF];
#pragma unroll
        for (int mf = 0; mf < MF; ++mf)
            af[mf] = *(const short8*)&As[(wm * (BM / 2) + mf * 16 + ml) * 32 + kq * 8];
#pragma unroll
        for (int nf = 0; nf < NF; ++nf)
            bfr[nf] = *(const short8*)&Bs[(wn * (BN / 2) + nf * 16 + ml) * 32 + kq * 8];
#pragma unroll
        for (int mf = 0; mf < MF; ++mf)
#pragma unroll
            for (int nf = 0; nf < NF; ++nf)
                acc[mf][nf] = __builtin_amdgcn_mfma_f32_16x16x32_bf16(
                    af[mf], bfr[nf], acc[mf][nf], 0, 0, 0);
    }

    const int rq = lane >> 4;
#pragma unroll
    for (int mf = 0; mf < MF; ++mf)
#pragma unroll
        for (int nf = 0; nf < NF; ++nf) {
            const int col = n0 + wn * (BN / 2) + nf * 16 + ml;
            const float bv = bias ? bias[col] : 0.f;
#pragma unroll
            for (int r = 0; r < 4; ++r) {
                const int row = m0 + wm * (BM / 2) + mf * 16 + rq * 4 + r;
                float v = scale * (acc[mf][nf][r] + bv);
                const size_t idx = cOff + (size_t)row * ldc + col;
                if (res1) v += res1[idx];
                if (res2) v += res2[idx];
                if (relu) v = fmaxf(v, 0.f);
                if (Cf) Cf[idx] = v;
                if (Ch) Ch[idx] = f2bf(v);
            }
        }
}

// ---------------------------------------------------------------------------
// P @ V per (b,h): 64(i) x 64(d) tile, BK=32 over S. V staged TRANSPOSED in
// LDS ([d][k], stride 40 u16 => 16B-aligned rows) so B-frags are ds_read_b128.
// Grid: (L/64, 16).
// ---------------------------------------------------------------------------
__global__ __launch_bounds__(256) void mfma_pv(
    const u16* __restrict__ P,
    const u16* __restrict__ V, int ldv,
    u16* __restrict__ att, int L, int S)
{
    __shared__ u16 Ps[64 * 32];
    __shared__ u16 VsT[64 * 40];

    const int tid = threadIdx.x;
    const int wave = tid >> 6, lane = tid & 63;
    const int wm = wave >> 1, wn = wave & 1;
    const int i0 = blockIdx.x * 64;
    const int bz = blockIdx.y, bb = bz & 1, hh = bz >> 1;
    const u16* Pb = P + (size_t)bz * L * S;

    const int ar = tid >> 2, ac = (tid & 3) * 8;
    const int vk = tid >> 3, vd = (tid & 7) * 8;
    const int ml = lane & 15, kq = lane >> 4;

    f32x4 acc[2][2];
#pragma unroll
    for (int mf = 0; mf < 2; ++mf)
#pragma unroll
        for (int nf = 0; nf < 2; ++nf) acc[mf][nf] = (f32x4){0.f, 0.f, 0.f, 0.f};

    for (int k0 = 0; k0 < S; k0 += 32) {
        __syncthreads();
        *(short8*)&Ps[ar * 32 + ac] =
            *(const short8*)&Pb[(size_t)(i0 + ar) * S + k0 + ac];
        const short8 v =
            *(const short8*)&V[(size_t)((k0 + vk) * 2 + bb) * ldv + hh * 64 + vd];
#pragma unroll
        for (int j = 0; j < 8; ++j) VsT[(vd + j) * 40 + vk] = (u16)v[j];
        __syncthreads();

        short8 af[2], bfr[2];
#pragma unroll
        for (int mf = 0; mf < 2; ++mf)
            af[mf] = *(const short8*)&Ps[(wm * 32 + mf * 16 + ml) * 32 + kq * 8];
#pragma unroll
        for (int nf = 0; nf < 2; ++nf)
            bfr[nf] = *(const short8*)&VsT[(wn * 32 + nf * 16 + ml) * 40 + kq * 8];
#pragma unroll
        for (int mf = 0; mf < 2; ++mf)
#pragma unroll
            for (int nf = 0; nf < 2; ++nf)
                acc[mf][nf] = __builtin_amdgcn_mfma_f32_16x16x32_bf16(
                    af[mf], bfr[nf], acc[mf][nf], 0, 0, 0);
    }

    const int rq = lane >> 4;
#pragma unroll
    for (int mf = 0; mf < 2; ++mf)
#pragma unroll
        for (int nf = 0; nf < 2; ++nf) {
            const int d = wn * 32 + nf * 16 + ml;
#pragma unroll
            for (int r = 0; r < 4; ++r) {
                const int i = i0 + wm * 32 + mf * 16 + rq * 4 + r;
                att[((size_t)i * 2 + bb) * 512 + hh * 64 + d] = f2bf(acc[mf][nf][r]);
            }
        }
}

// ---------------------------------------------------------------------------
// In-place row softmax on bf16 rows. grid = nRows.
// ---------------------------------------------------------------------------
__global__ __launch_bounds__(256) void softmax_bf(u16* __restrict__ X, int S) {
    __shared__ float sc[2048];
    __shared__ float red[256];
    const int tid = threadIdx.x;
    u16* xr = X + (size_t)blockIdx.x * S;
    float lmax = -1e30f;
    for (int s = tid; s < S; s += 256) {
        const float v = bf2f(xr[s]); sc[s] = v; lmax = fmaxf(lmax, v);
    }
    red[tid] = lmax; __syncthreads();
    for (int st = 128; st; st >>= 1) {
        if (tid < st) red[tid] = fmaxf(red[tid], red[tid + st]);
        __syncthreads();
    }
    const float mx = red[0]; __syncthreads();
    float lsum = 0.f;
    for (int s = tid; s < S; s += 256) {
        const float p = __expf(sc[s] - mx); sc[s] = p; lsum += p;
    }
    red[tid] = lsum; __syncthreads();
    for (int st = 128; st; st >>= 1) {
        if (tid < st) red[tid] += red[tid + st];
        __syncthreads();
    }
    const float inv = 1.0f / red[0];
    for (int s = tid; s < S; s += 256) xr[s] = f2bf(sc[s] * inv);
}

// ---------------------------------------------------------------------------
// Head-average of bf16 probs + second softmax -> fp32 out (1 or 2 copies).
// grid = 2*L, blockIdx.x = b*L + i.
// ---------------------------------------------------------------------------
__global__ __launch_bounds__(256) void avg_softmax(
    const u16* __restrict__ P, int L, int S,
    float* __restrict__ out1, float* __restrict__ out2)
{
    __shared__ float wacc[2048];
    __shared__ float red[256];
    const int tid = threadIdx.x;
    const int b = blockIdx.x / L, i = blockIdx.x % L;
    const size_t LS = (size_t)L * S;

    for (int s = tid; s < S; s += 256) {
        float sum = 0.f;
#pragma unroll
        for (int h = 0; h < 8; ++h)
            sum += bf2f(P[(size_t)(h * 2 + b) * LS + (size_t)i * S + s]);
        wacc[s] = sum * 0.125f;
    }
    __syncthreads();
    float lmax = -1e30f;
    for (int s = tid; s < S; s += 256) lmax = fmaxf(lmax, wacc[s]);
    red[tid] = lmax; __syncthreads();
    for (int st = 128; st; st >>= 1) {
        if (tid < st) red[tid] = fmaxf(red[tid], red[tid + st]);
        __syncthreads();
    }
    const float mx = red[0]; __syncthreads();
    float lsum = 0.f;
    for (int s = tid; s < S; s += 256) {
        const float p = __expf(wacc[s] - mx); wacc[s] = p; lsum += p;
    }
    red[tid] = lsum; __syncthreads();
    for (int st = 128; st; st >>= 1) {
        if (tid < st) red[tid] += red[tid + st];
        __syncthreads();
    }
    const float inv = 1.0f / red[0];
    const size_t rbase = (size_t)blockIdx.x * S;
    for (int s = tid; s < S; s += 256) {
        const float p = wacc[s] * inv;
        out1[rbase + s] = p;
        if (out2) out2[rbase + s] = p;
    }
}

// ---------------------------------------------------------------------------
// LayerNorm over rows of 512; fp32 out + optional bf16 out.
// ---------------------------------------------------------------------------
__global__ __launch_bounds__(256) void ln512(
    const float* __restrict__ X, const float* __restrict__ g,
    const float* __restrict__ be, float* __restrict__ Yf, u16* __restrict__ Yb)
{
    __shared__ float red[256];
    const int r = blockIdx.x, tid = threadIdx.x;
    const float* xr = X + (size_t)r * 512;
    const float x0 = xr[tid], x1 = xr[tid + 256];
    red[tid] = x0 + x1; __syncthreads();
    for (int st = 128; st; st >>= 1) {
        if (tid < st) red[tid] += red[tid + st];
        __syncthreads();
    }
    const float mean = red[0] * (1.0f / 512.0f); __syncthreads();
    const float d0 = x0 - mean, d1 = x1 - mean;
    red[tid] = d0 * d0 + d1 * d1; __syncthreads();
    for (int st = 128; st; st >>= 1) {
        if (tid < st) red[tid] += red[tid + st];
        __syncthreads();
    }
    const float rstd = rsqrtf(red[0] * (1.0f / 512.0f) + LN_EPS);
    const float y0 = d0 * rstd * g[tid] + be[tid];
    const float y1 = d1 * rstd * g[tid + 256] + be[tid + 256];
    float* yr = Yf + (size_t)r * 512;
    yr[tid] = y0; yr[tid + 256] = y1;
    if (Yb) {
        u16* yb = Yb + (size_t)r * 512;
        yb[tid] = f2bf(y0); yb[tid + 256] = f2bf(y1);
    }
}

// ---------------------------------------------------------------------------
// pair assembly: inverse map + gather rows to bf16.
// ---------------------------------------------------------------------------
__global__ void init_inv(int* __restrict__ inv) {
    const int i = blockIdx.x * 256 + threadIdx.x;
    if (i < 4096) inv[i] = -1;
}
__global__ void scatter_inv(int* __restrict__ inv, const int* __restrict__ ind, int n) {
    const int i = blockIdx.x * 256 + threadIdx.x;
    if (i < n) inv[ind[i]] = i;
}
__global__ void gather_rows_bf(
    u16* __restrict__ dst, const float* __restrict__ spf,
    const float* __restrict__ ep, const int* __restrict__ ind,
    const int* __restrict__ inv, int total4)
{
    const int e = blockIdx.x * 256 + threadIdx.x;
    if (e >= total4) return;
    const int row = e >> 7, c = e & 127;
    const int j = row >> 1, b = row & 1;
    const int idx = ind[j];
    const int iv = inv[idx];
    const float4* src = (iv >= 0) ? (const float4*)(spf + (size_t)(iv * 2 + b) * 512)
                                  : (const float4*)(ep + (size_t)(idx * 2 + b) * 512);
    const float4 v = src[c];
    ushort4 o; o.x = f2bf(v.x); o.y = f2bf(v.y); o.z = f2bf(v.z); o.w = f2bf(v.w);
    ((ushort4*)dst)[e] = o;
}

// ---------------------------------------------------------------------------
extern "C" void kernel_launch(void* const* d_in, const int* in_sizes, int n_in,
                              void* d_out, int out_size, void* d_ws, size_t ws_size,
                              hipStream_t stream)
{
    (void)in_sizes; (void)n_in; (void)out_size; (void)ws_size;

    const float* in_sp = (const float*)d_in[0];
    const float* in_su = (const float*)d_in[1];
    const float* in_ep = (const float*)d_in[2];
    const int* ind_pair = (const int*)d_in[3];
    const int* ind_e2e  = (const int*)d_in[4];
    const int* ind_n2e  = (const int*)d_in[5];
    const float *Wi_sa  = (const float*)d_in[6],  *bi_sa  = (const float*)d_in[7];
    const float *Wo_sa  = (const float*)d_in[8],  *bo_sa  = (const float*)d_in[9];
    const float *Wi_san = (const float*)d_in[10], *bi_san = (const float*)d_in[11];
    const float *Wo_san = (const float*)d_in[12], *bo_san = (const float*)d_in[13];
    const float *Wi_e2e = (const float*)d_in[14], *bi_e2e = (const float*)d_in[15];
    const float *Wo_e2e = (const float*)d_in[16], *bo_e2e = (const float*)d_in[17];
    const float *Wi_n2e = (const float*)d_in[18], *bi_n2e = (const float*)d_in[19];
    const float *Wo_n2e = (const float*)d_in[20], *bo_n2e = (const float*)d_in[21];
    const float *Wi_n2n = (const float*)d_in[22], *bi_n2n = (const float*)d_in[23];
    const float *Wo_n2n = (const float*)d_in[24], *bo_n2n = (const float*)d_in[25];
    const float *W1  = (const float*)d_in[26], *b1f  = (const float*)d_in[27];
    const float *W2  = (const float*)d_in[28], *b2f  = (const float*)d_in[29];
    const float *W1u = (const float*)d_in[30], *b1fu = (const float*)d_in[31];
    const float *W2u = (const float*)d_in[32], *b2fu = (const float*)d_in[33];
    const float *g1  = (const float*)d_in[34], *g1u = (const float*)d_in[35];
    const float *g2  = (const float*)d_in[36], *g3  = (const float*)d_in[37];
    const float *be1 = (const float*)d_in[38], *be1u = (const float*)d_in[39];
    const float *be2 = (const float*)d_in[40], *be3  = (const float*)d_in[41];

    float* Wf = (float*)d_ws;
    size_t of = 0;
    auto af_ = [&](size_t n) { float* p = Wf + of; of += n; return p; };
    float* spf    = af_((size_t)2048 * 512);
    float* suf    = af_((size_t)512 * 512);
    float* tmp0f  = af_((size_t)2048 * 512);
    float* tmp1f  = af_((size_t)2048 * 512);
    float* upn2ef = af_((size_t)512 * 512);

    u16* Wu = (u16*)(Wf + of);
    size_t ou = 0;
    auto au_ = [&](size_t n) { u16* p = Wu + ou; ou += n; return p; };
    u16* in_spb = au_((size_t)2048 * 512);
    u16* in_sub = au_((size_t)512 * 512);
    u16* spb    = au_((size_t)2048 * 512);
    u16* sub    = au_((size_t)512 * 512);
    u16* ge2eb  = au_((size_t)4096 * 512);
    u16* gn2eb  = au_((size_t)4096 * 512);
    u16* qkvb   = au_((size_t)2048 * 1536);
    u16* kvb    = au_((size_t)4096 * 1024);
    u16* attb   = au_((size_t)2048 * 512);
    u16* tmp1b  = au_((size_t)2048 * 512);
    u16* ffnb   = au_((size_t)2048 * 2048);
    u16* probs  = au_((size_t)16 * 1024 * 2048);
    u16* wb[14];
    const int wsz[14] = {786432, 262144, 786432, 262144, 786432, 262144, 786432,
                         262144, 786432, 262144, 1048576, 1048576, 1048576, 1048576};
    for (int i = 0; i < 14; ++i) wb[i] = au_((size_t)wsz[i]);
    int* inv = (int*)(Wu + ou);

    float* out_uu = (float*)d_out;
    float* out_up = out_uu + 262144;
    float* out_w1 = out_up + 1048576;
    float* out_w2 = out_w1 + 4194304;
    float* out_w3 = out_w2 + 4194304;
    float* out_w4 = out_w3 + 1048576;

    const dim3 blk(256);

    CvtDesc cd;
    const float* wsrc[14] = {Wi_sa, Wo_sa, Wi_san, Wo_san, Wi_e2e, Wo_e2e, Wi_n2e,
                             Wo_n2e, Wi_n2n, Wo_n2n, W1, W2, W1u, W2u};
    for (int i = 0; i < 14; ++i) { cd.src[i] = wsrc[i]; cd.dst[i] = wb[i]; cd.n4[i] = wsz[i] / 4; }
    cd.src[14] = in_sp; cd.dst[14] = in_spb; cd.n4[14] = 1048576 / 4;
    cd.src[15] = in_su; cd.dst[15] = in_sub; cd.n4[15] = 262144 / 4;
    cvt_multi<<<dim3(1024, 16), blk, 0, stream>>>(cd);

    init_inv<<<16, blk, 0, stream>>>(inv);
    scatter_inv<<<4, blk, 0, stream>>>(inv, ind_pair, 1024);

    // tile=64 for shapes whose 128-grid would under-fill the 256 CUs
    auto gemm = [&](int tile, const u16* A, int lda, int aOffB, int aOffH,
                    const u16* B, int ldb, int bOffB, int bOffH,
                    float* Cf, u16* Ch, int ldc, long cOffB, long cOffH,
                    const float* bias, const float* r1, const float* r2,
                    float scale, int relu, int M, int N, int K, int batch) {
        if (tile == 64)
            mfma_gemm<64, 64><<<dim3(N / 64, M / 64, batch), blk, 0, stream>>>(
                A, lda, aOffB, aOffH, B, ldb, bOffB, bOffH, Cf, Ch, ldc, cOffB, cOffH,
                bias, r1, r2, scale, relu, K);
        else
            mfma_gemm<128, 128><<<dim3(N / 128, M / 128, batch), blk, 0, stream>>>(
                A, lda, aOffB, aOffH, B, ldb, bOffB, bOffH, Cf, Ch, ldc, cOffB, cOffH,
                bias, r1, r2, scale, relu, K);
    };

    // ================= self-attention (pair) =================
    gemm(128, in_spb, 512, 0, 0, wb[0], 512, 0, 0, nullptr, qkvb, 1536, 0, 0,
         bi_sa, nullptr, nullptr, 1.f, 0, 2048, 1536, 512, 1);
    gemm(128, qkvb, 3072, 1536, 64, qkvb + 512, 3072, 1536, 64, nullptr, probs,
         1024, 1048576L, 2097152L, nullptr, nullptr, nullptr, 0.125f, 0, 1024, 1024, 64, 16);
    softmax_bf<<<16384, blk, 0, stream>>>(probs, 1024);
    mfma_pv<<<dim3(16, 16), blk, 0, stream>>>(probs, qkvb + 1024, 1536, attb, 1024, 1024);
    gemm(64, attb, 512, 0, 0, wb[1], 512, 0, 0, tmp0f, nullptr, 512, 0, 0,
         bo_sa, in_sp, nullptr, 1.f, 0, 2048, 512, 512, 1);
    ln512<<<2048, blk, 0, stream>>>(tmp0f, g1, be1, spf, spb);

    // ================= self-attention (unary) =================
    gemm(64, in_sub, 512, 0, 0, wb[2], 512, 0, 0, nullptr, qkvb, 1536, 0, 0,
         bi_san, nullptr, nullptr, 1.f, 0, 512, 1536, 512, 1);
    gemm(64, qkvb, 3072, 1536, 64, qkvb + 512, 3072, 1536, 64, nullptr, probs,
         256, 65536L, 131072L, nullptr, nullptr, nullptr, 0.125f, 0, 256, 256, 64, 16);
    softmax_bf<<<4096, blk, 0, stream>>>(probs, 256);
    mfma_pv<<<dim3(4, 16), blk, 0, stream>>>(probs, qkvb + 1024, 1536, attb, 256, 256);
    gemm(64, attb, 512, 0, 0, wb[3], 512, 0, 0, tmp0f, nullptr, 512, 0, 0,
         bo_san, in_su, nullptr, 1.f, 0, 512, 512, 512, 1);
    ln512<<<512, blk, 0, stream>>>(tmp0f, g1u, be1u, suf, sub);

    // ================= gathers =================
    gather_rows_bf<<<2048, blk, 0, stream>>>(ge2eb, spf, in_ep, ind_e2e, inv, 524288);
    gather_rows_bf<<<2048, blk, 0, stream>>>(gn2eb, spf, in_ep, ind_n2e, inv, 524288);

    // ================= e2e cross-attention =================
    gemm(64, spb, 512, 0, 0, wb[4], 512, 0, 0, nullptr, qkvb, 512, 0, 0,
         bi_e2e, nullptr, nullptr, 1.f, 0, 2048, 512, 512, 1);
    gemm(128, ge2eb, 512, 0, 0, wb[4] + 262144, 512, 0, 0, nullptr, kvb, 1024, 0, 0,
         bi_e2e + 512, nullptr, nullptr, 1.f, 0, 4096, 1024, 512, 1);
    gemm(128, qkvb, 1024, 512, 64, kvb, 2048, 1024, 64, nullptr, probs,
         2048, 2097152L, 4194304L, nullptr, nullptr, nullptr, 0.125f, 0, 1024, 2048, 64, 16);
    softmax_bf<<<16384, blk, 0, stream>>>(probs, 2048);
    mfma_pv<<<dim3(16, 16), blk, 0, stream>>>(probs, kvb + 512, 1024, attb, 1024, 2048);
    avg_softmax<<<2048, blk, 0, stream>>>(probs, 1024, 2048, out_w1, out_w2);
    gemm(64, attb, 512, 0, 0, wb[5], 512, 0, 0, tmp0f, nullptr, 512, 0, 0,
         bo_e2e, spf, nullptr, 2.f, 0, 2048, 512, 512, 1);
    ln512<<<2048, blk, 0, stream>>>(tmp0f, g2, be2, tmp1f, tmp1b);
    // FFN (pair)
    gemm(128, tmp1b, 512, 0, 0, wb[10], 512, 0, 0, nullptr, ffnb, 2048, 0, 0,
         b1f, nullptr, nullptr, 1.f, 1, 2048, 2048, 512, 1);
    gemm(64, ffnb, 2048, 0, 0, wb[11], 2048, 0, 0, tmp0f, nullptr, 512, 0, 0,
         b2f, tmp1f, nullptr, 1.f, 0, 2048, 512, 2048, 1);
    ln512<<<2048, blk, 0, stream>>>(tmp0f, g3, be3, out_up, nullptr);

    // ================= n2e cross-attention =================
    gemm(64, sub, 512, 0, 0, wb[6], 512, 0, 0, nullptr, qkvb, 512, 0, 0,
         bi_n2e, nullptr, nullptr, 1.f, 0, 512, 512, 512, 1);
    gemm(128, gn2eb, 512, 0, 0, wb[6] + 262144, 512, 0, 0, nullptr, kvb, 1024, 0, 0,
         bi_n2e + 512, nullptr, nullptr, 1.f, 0, 4096, 1024, 512, 1);
    gemm(128, qkvb, 1024, 512, 64, kvb, 2048, 1024, 64, nullptr, probs,
         2048, 524288L, 1048576L, nullptr, nullptr, nullptr, 0.125f, 0, 256, 2048, 64, 16);
    softmax_bf<<<4096, blk, 0, stream>>>(probs, 2048);
    mfma_pv<<<dim3(4, 16), blk, 0, stream>>>(probs, kvb + 512, 1024, attb, 256, 2048);
    avg_softmax<<<512, blk, 0, stream>>>(probs, 256, 2048, out_w3, nullptr);
    gemm(64, attb, 512, 0, 0, wb[7], 512, 0, 0, upn2ef, nullptr, 512, 0, 0,
         bo_n2e, nullptr, nullptr, 1.f, 0, 512, 512, 512, 1);

    // ================= n2n self-attention =================
    gemm(64, sub, 512, 0, 0, wb[8], 512, 0, 0, nullptr, qkvb, 1536, 0, 0,
         bi_n2n, nullptr, nullptr, 1.f, 0, 512, 1536, 512, 1);
    gemm(64, qkvb, 3072, 1536, 64, qkvb + 512, 3072, 1536, 64, nullptr, probs,
         256, 65536L, 131072L, nullptr, nullptr, nullptr, 0.125f, 0, 256, 256, 64, 16);
    softmax_bf<<<4096, blk, 0, stream>>>(probs, 256);
    mfma_pv<<<dim3(4, 16), blk, 0, stream>>>(probs, qkvb + 1024, 1536, attb, 256, 256);
    avg_softmax<<<512, blk, 0, stream>>>(probs, 256, 256, out_w4, nullptr);
    gemm(64, attb, 512, 0, 0, wb[9], 512, 0, 0, tmp0f, nullptr, 512, 0, 0,
         bo_n2n, suf, upn2ef, 1.f, 0, 512, 512, 512, 1);
    ln512<<<512, blk, 0, stream>>>(tmp0f, g2, be2, tmp1f, tmp1b);
    // FFN (unary)
    gemm(64, tmp1b, 512, 0, 0, wb[12], 512, 0, 0, nullptr, ffnb, 2048, 0, 0,
         b1fu, nullptr, nullptr, 1.f, 1, 512, 2048, 512, 1);
    gemm(64, ffnb, 2048, 0, 0, wb[13], 2048, 0, 0, tmp0f, nullptr, 512, 0, 0,
         b2fu, tmp1f, nullptr, 1.f, 0, 512, 512, 2048, 1);
    ln512<<<512, blk, 0, stream>>>(tmp0f, g3, be3, out_uu, nullptr);
}

// Round 5
// 783.621 us; speedup vs baseline: 8.4363x; 1.0401x over previous
//
#include <hip/hip_runtime.h>
#include <cstddef>

#define LN_EPS 1e-5f

typedef unsigned short u16;
typedef short short8 __attribute__((ext_vector_type(8)));
typedef float f32x4 __attribute__((ext_vector_type(4)));

__device__ __forceinline__ u16 f2bf(float f) {
    unsigned int u = __float_as_uint(f);
    u = (u + 0x7FFFu + ((u >> 16) & 1u)) >> 16;
    return (u16)u;
}
__device__ __forceinline__ float bf2f(u16 h) {
    return __uint_as_float((unsigned int)h << 16);
}

// ---------------------------------------------------------------------------
// Multi-tensor fp32 -> bf16 convert (weights + inputs), one launch.
// ---------------------------------------------------------------------------
struct CvtDesc {
    const float* src[16];
    u16* dst[16];
    int n4[16];
};
__global__ __launch_bounds__(256) void cvt_multi(CvtDesc d) {
    const int t = blockIdx.x * 256 + threadIdx.x;
    const int i = blockIdx.y;
    if (t >= d.n4[i]) return;
    const float4 v = ((const float4*)d.src[i])[t];
    ushort4 o;
    o.x = f2bf(v.x); o.y = f2bf(v.y); o.z = f2bf(v.z); o.w = f2bf(v.w);
    ((ushort4*)d.dst[i])[t] = o;
}

// ---------------------------------------------------------------------------
// bf16 MFMA NT GEMM, BMxBN tile, 4 waves (2x2), BK=32, 16x16x32 MFMA.
// C = scale*(A@B^T + bias) + res1 + res2 (+relu). Outputs fp32 and/or bf16.
// Batched over grid.z: bz -> (b = bz&1, h = bz>>1) offsets for A/B/C.
// ---------------------------------------------------------------------------
template<int BM, int BN>
__global__ __launch_bounds__(256) void mfma_gemm(
    const u16* __restrict__ A, int lda, int aOffB, int aOffH,
    const u16* __restrict__ B, int ldb, int bOffB, int bOffH,
    float* __restrict__ Cf, u16* __restrict__ Ch,
    int ldc, long cOffB, long cOffH,
    const float* __restrict__ bias,
    const float* __restrict__ res1, const float* __restrict__ res2,
    float scale, int relu, int K)
{
    constexpr int MF = BM / 32;
    constexpr int NF = BN / 32;
    __shared__ u16 As[BM * 32];
    __shared__ u16 Bs[BN * 32];

    const int tid = threadIdx.x;
    const int wave = tid >> 6, lane = tid & 63;
    const int wm = wave >> 1, wn = wave & 1;
    const int m0 = blockIdx.y * BM, n0 = blockIdx.x * BN;
    const int bz = blockIdx.z, bb = bz & 1, hh = bz >> 1;
    const size_t aOff = (size_t)bb * aOffB + (size_t)hh * aOffH;
    const size_t bOff = (size_t)bb * bOffB + (size_t)hh * bOffH;
    const size_t cOff = (size_t)bb * cOffB + (size_t)hh * cOffH;

    f32x4 acc[MF][NF];
#pragma unroll
    for (int mf = 0; mf < MF; ++mf)
#pragma unroll
        for (int nf = 0; nf < NF; ++nf) acc[mf][nf] = (f32x4){0.f, 0.f, 0.f, 0.f};

    const int ar = tid >> 2, ac = (tid & 3) * 8;
    const int ml = lane & 15, kq = lane >> 4;

    for (int k0 = 0; k0 < K; k0 += 32) {
        __syncthreads();
#pragma unroll
        for (int c = 0; c < BM / 64; ++c) {
            const int r = ar + c * 64;
            *(short8*)&As[r * 32 + ac] =
                *(const short8*)&A[aOff + (size_t)(m0 + r) * lda + k0 + ac];
        }
#pragma unroll
        for (int c = 0; c < BN / 64; ++c) {
            const int r = ar + c * 64;
            *(short8*)&Bs[r * 32 + ac] =
                *(const short8*)&B[bOff + (size_t)(n0 + r) * ldb + k0 + ac];
        }
        __syncthreads();

        short8 af[MF], bfr[NF];
#pragma unroll
        for (int mf = 0; mf < MF; ++mf)
            af[mf] = *(const short8*)&As[(wm * (BM / 2) + mf * 16 + ml) * 32 + kq * 8];
#pragma unroll
        for (int nf = 0; nf < NF; ++nf)
            bfr[nf] = *(const short8*)&Bs[(wn * (BN / 2) + nf * 16 + ml) * 32 + kq * 8];
#pragma unroll
        for (int mf = 0; mf < MF; ++mf)
#pragma unroll
            for (int nf = 0; nf < NF; ++nf)
                acc[mf][nf] = __builtin_amdgcn_mfma_f32_16x16x32_bf16(
                    af[mf], bfr[nf], acc[mf][nf], 0, 0, 0);
    }

    const int rq = lane >> 4;
#pragma unroll
    for (int mf = 0; mf < MF; ++mf)
#pragma unroll
        for (int nf = 0; nf < NF; ++nf) {
            const int col = n0 + wn * (BN / 2) + nf * 16 + ml;
            const float bv = bias ? bias[col] : 0.f;
#pragma unroll
            for (int r = 0; r < 4; ++r) {
                const int row = m0 + wm * (BM / 2) + mf * 16 + rq * 4 + r;
                float v = scale * (acc[mf][nf][r] + bv);
                const size_t idx = cOff + (size_t)row * ldc + col;
                if (res1) v += res1[idx];
                if (res2) v += res2[idx];
                if (relu) v = fmaxf(v, 0.f);
                if (Cf) Cf[idx] = v;
                if (Ch) Ch[idx] = f2bf(v);
            }
        }
}

// ---------------------------------------------------------------------------
// One-time V transpose: vT[bh][d][s] = V[(s*2+b)*ldv + h*64 + d]  (bf16).
// LDS-tiled, coalesced global on both sides. Grid: (S/64, 16).
// ---------------------------------------------------------------------------
__global__ __launch_bounds__(256) void vtrans(
    const u16* __restrict__ V, int ldv, u16* __restrict__ vT, int S)
{
    __shared__ u16 Vs[64 * 72];   // [s_local][d], stride 72 (8-aligned, bank-shifted)
    const int tid = threadIdx.x;
    const int s0 = blockIdx.x * 64;
    const int bh = blockIdx.y, b = bh & 1, h = bh >> 1;

#pragma unroll
    for (int c = 0; c < 2; ++c) {
        const int idx = tid + c * 256;
        const int sr = idx >> 3, dc = (idx & 7) * 8;
        *(short8*)&Vs[sr * 72 + dc] =
            *(const short8*)&V[(size_t)((s0 + sr) * 2 + b) * ldv + h * 64 + dc];
    }
    __syncthreads();
#pragma unroll
    for (int c = 0; c < 2; ++c) {
        const int idx = tid + c * 256;
        const int dr = idx >> 3, sc = (idx & 7) * 8;
        short8 o;
#pragma unroll
        for (int j = 0; j < 8; ++j) o[j] = (short)Vs[(sc + j) * 72 + dr];
        *(short8*)&vT[(size_t)bh * 64 * S + (size_t)dr * S + s0 + sc] = o;
    }
}

// ---------------------------------------------------------------------------
// In-place row softmax on bf16 rows. grid = nRows.
// ---------------------------------------------------------------------------
__global__ __launch_bounds__(256) void softmax_bf(u16* __restrict__ X, int S) {
    __shared__ float sc[2048];
    __shared__ float red[256];
    const int tid = threadIdx.x;
    u16* xr = X + (size_t)blockIdx.x * S;
    float lmax = -1e30f;
    for (int s = tid; s < S; s += 256) {
        const float v = bf2f(xr[s]); sc[s] = v; lmax = fmaxf(lmax, v);
    }
    red[tid] = lmax; __syncthreads();
    for (int st = 128; st; st >>= 1) {
        if (tid < st) red[tid] = fmaxf(red[tid], red[tid + st]);
        __syncthreads();
    }
    const float mx = red[0]; __syncthreads();
    float lsum = 0.f;
    for (int s = tid; s < S; s += 256) {
        const float p = __expf(sc[s] - mx); sc[s] = p; lsum += p;
    }
    red[tid] = lsum; __syncthreads();
    for (int st = 128; st; st >>= 1) {
        if (tid < st) red[tid] += red[tid + st];
        __syncthreads();
    }
    const float inv = 1.0f / red[0];
    for (int s = tid; s < S; s += 256) xr[s] = f2bf(sc[s] * inv);
}

// ---------------------------------------------------------------------------
// Head-average of bf16 probs + second softmax -> fp32 out (1 or 2 copies).
// grid = 2*L, blockIdx.x = b*L + i.
// ---------------------------------------------------------------------------
__global__ __launch_bounds__(256) void avg_softmax(
    const u16* __restrict__ P, int L, int S,
    float* __restrict__ out1, float* __restrict__ out2)
{
    __shared__ float wacc[2048];
    __shared__ float red[256];
    const int tid = threadIdx.x;
    const int b = blockIdx.x / L, i = blockIdx.x % L;
    const size_t LS = (size_t)L * S;

    for (int s = tid; s < S; s += 256) {
        float sum = 0.f;
#pragma unroll
        for (int h = 0; h < 8; ++h)
            sum += bf2f(P[(size_t)(h * 2 + b) * LS + (size_t)i * S + s]);
        wacc[s] = sum * 0.125f;
    }
    __syncthreads();
    float lmax = -1e30f;
    for (int s = tid; s < S; s += 256) lmax = fmaxf(lmax, wacc[s]);
    red[tid] = lmax; __syncthreads();
    for (int st = 128; st; st >>= 1) {
        if (tid < st) red[tid] = fmaxf(red[tid], red[tid + st]);
        __syncthreads();
    }
    const float mx = red[0]; __syncthreads();
    float lsum = 0.f;
    for (int s = tid; s < S; s += 256) {
        const float p = __expf(wacc[s] - mx); wacc[s] = p; lsum += p;
    }
    red[tid] = lsum; __syncthreads();
    for (int st = 128; st; st >>= 1) {
        if (tid < st) red[tid] += red[tid + st];
        __syncthreads();
    }
    const float inv = 1.0f / red[0];
    const size_t rbase = (size_t)blockIdx.x * S;
    for (int s = tid; s < S; s += 256) {
        const float p = wacc[s] * inv;
        out1[rbase + s] = p;
        if (out2) out2[rbase + s] = p;
    }
}

// ---------------------------------------------------------------------------
// LayerNorm over rows of 512; fp32 out + optional bf16 out.
// ---------------------------------------------------------------------------
__global__ __launch_bounds__(256) void ln512(
    const float* __restrict__ X, const float* __restrict__ g,
    const float* __restrict__ be, float* __restrict__ Yf, u16* __restrict__ Yb)
{
    __shared__ float red[256];
    const int r = blockIdx.x, tid = threadIdx.x;
    const float* xr = X + (size_t)r * 512;
    const float x0 = xr[tid], x1 = xr[tid + 256];
    red[tid] = x0 + x1; __syncthreads();
    for (int st = 128; st; st >>= 1) {
        if (tid < st) red[tid] += red[tid + st];
        __syncthreads();
    }
    const float mean = red[0] * (1.0f / 512.0f); __syncthreads();
    const float d0 = x0 - mean, d1 = x1 - mean;
    red[tid] = d0 * d0 + d1 * d1; __syncthreads();
    for (int st = 128; st; st >>= 1) {
        if (tid < st) red[tid] += red[tid + st];
        __syncthreads();
    }
    const float rstd = rsqrtf(red[0] * (1.0f / 512.0f) + LN_EPS);
    const float y0 = d0 * rstd * g[tid] + be[tid];
    const float y1 = d1 * rstd * g[tid + 256] + be[tid + 256];
    float* yr = Yf + (size_t)r * 512;
    yr[tid] = y0; yr[tid + 256] = y1;
    if (Yb) {
        u16* yb = Yb + (size_t)r * 512;
        yb[tid] = f2bf(y0); yb[tid + 256] = f2bf(y1);
    }
}

// ---------------------------------------------------------------------------
// pair assembly: inverse map + gather rows to bf16.
// ---------------------------------------------------------------------------
__global__ void init_inv(int* __restrict__ inv) {
    const int i = blockIdx.x * 256 + threadIdx.x;
    if (i < 4096) inv[i] = -1;
}
__global__ void scatter_inv(int* __restrict__ inv, const int* __restrict__ ind, int n) {
    const int i = blockIdx.x * 256 + threadIdx.x;
    if (i < n) inv[ind[i]] = i;
}
__global__ void gather_rows_bf(
    u16* __restrict__ dst, const float* __restrict__ spf,
    const float* __restrict__ ep, const int* __restrict__ ind,
    const int* __restrict__ inv, int total4)
{
    const int e = blockIdx.x * 256 + threadIdx.x;
    if (e >= total4) return;
    const int row = e >> 7, c = e & 127;
    const int j = row >> 1, b = row & 1;
    const int idx = ind[j];
    const int iv = inv[idx];
    const float4* src = (iv >= 0) ? (const float4*)(spf + (size_t)(iv * 2 + b) * 512)
                                  : (const float4*)(ep + (size_t)(idx * 2 + b) * 512);
    const float4 v = src[c];
    ushort4 o; o.x = f2bf(v.x); o.y = f2bf(v.y); o.z = f2bf(v.z); o.w = f2bf(v.w);
    ((ushort4*)dst)[e] = o;
}

// ---------------------------------------------------------------------------
extern "C" void kernel_launch(void* const* d_in, const int* in_sizes, int n_in,
                              void* d_out, int out_size, void* d_ws, size_t ws_size,
                              hipStream_t stream)
{
    (void)in_sizes; (void)n_in; (void)out_size; (void)ws_size;

    const float* in_sp = (const float*)d_in[0];
    const float* in_su = (const float*)d_in[1];
    const float* in_ep = (const float*)d_in[2];
    const int* ind_pair = (const int*)d_in[3];
    const int* ind_e2e  = (const int*)d_in[4];
    const int* ind_n2e  = (const int*)d_in[5];
    const float *Wi_sa  = (const float*)d_in[6],  *bi_sa  = (const float*)d_in[7];
    const float *Wo_sa  = (const float*)d_in[8],  *bo_sa  = (const float*)d_in[9];
    const float *Wi_san = (const float*)d_in[10], *bi_san = (const float*)d_in[11];
    const float *Wo_san = (const float*)d_in[12], *bo_san = (const float*)d_in[13];
    const float *Wi_e2e = (const float*)d_in[14], *bi_e2e = (const float*)d_in[15];
    const float *Wo_e2e = (const float*)d_in[16], *bo_e2e = (const float*)d_in[17];
    const float *Wi_n2e = (const float*)d_in[18], *bi_n2e = (const float*)d_in[19];
    const float *Wo_n2e = (const float*)d_in[20], *bo_n2e = (const float*)d_in[21];
    const float *Wi_n2n = (const float*)d_in[22], *bi_n2n = (const float*)d_in[23];
    const float *Wo_n2n = (const float*)d_in[24], *bo_n2n = (const float*)d_in[25];
    const float *W1  = (const float*)d_in[26], *b1f  = (const float*)d_in[27];
    const float *W2  = (const float*)d_in[28], *b2f  = (const float*)d_in[29];
    const float *W1u = (const float*)d_in[30], *b1fu = (const float*)d_in[31];
    const float *W2u = (const float*)d_in[32], *b2fu = (const float*)d_in[33];
    const float *g1  = (const float*)d_in[34], *g1u = (const float*)d_in[35];
    const float *g2  = (const float*)d_in[36], *g3  = (const float*)d_in[37];
    const float *be1 = (const float*)d_in[38], *be1u = (const float*)d_in[39];
    const float *be2 = (const float*)d_in[40], *be3  = (const float*)d_in[41];

    float* Wf = (float*)d_ws;
    size_t of = 0;
    auto af_ = [&](size_t n) { float* p = Wf + of; of += n; return p; };
    float* spf    = af_((size_t)2048 * 512);
    float* suf    = af_((size_t)512 * 512);
    float* tmp0f  = af_((size_t)2048 * 512);
    float* tmp1f  = af_((size_t)2048 * 512);
    float* upn2ef = af_((size_t)512 * 512);

    u16* Wu = (u16*)(Wf + of);
    size_t ou = 0;
    auto au_ = [&](size_t n) { u16* p = Wu + ou; ou += n; return p; };
    u16* in_spb = au_((size_t)2048 * 512);
    u16* in_sub = au_((size_t)512 * 512);
    u16* spb    = au_((size_t)2048 * 512);
    u16* sub    = au_((size_t)512 * 512);
    u16* ge2eb  = au_((size_t)4096 * 512);
    u16* gn2eb  = au_((size_t)4096 * 512);
    u16* qkvb   = au_((size_t)2048 * 1536);
    u16* kvb    = au_((size_t)4096 * 1024);
    u16* attb   = au_((size_t)2048 * 512);
    u16* tmp1b  = au_((size_t)2048 * 512);
    u16* ffnb   = au_((size_t)2048 * 2048);
    u16* vtb    = au_((size_t)16 * 64 * 2048);
    u16* probs  = au_((size_t)16 * 1024 * 2048);
    u16* wb[14];
    const int wsz[14] = {786432, 262144, 786432, 262144, 786432, 262144, 786432,
                         262144, 786432, 262144, 1048576, 1048576, 1048576, 1048576};
    for (int i = 0; i < 14; ++i) wb[i] = au_((size_t)wsz[i]);
    int* inv = (int*)(Wu + ou);

    float* out_uu = (float*)d_out;
    float* out_up = out_uu + 262144;
    float* out_w1 = out_up + 1048576;
    float* out_w2 = out_w1 + 4194304;
    float* out_w3 = out_w2 + 4194304;
    float* out_w4 = out_w3 + 1048576;

    const dim3 blk(256);

    CvtDesc cd;
    const float* wsrc[14] = {Wi_sa, Wo_sa, Wi_san, Wo_san, Wi_e2e, Wo_e2e, Wi_n2e,
                             Wo_n2e, Wi_n2n, Wo_n2n, W1, W2, W1u, W2u};
    for (int i = 0; i < 14; ++i) { cd.src[i] = wsrc[i]; cd.dst[i] = wb[i]; cd.n4[i] = wsz[i] / 4; }
    cd.src[14] = in_sp; cd.dst[14] = in_spb; cd.n4[14] = 1048576 / 4;
    cd.src[15] = in_su; cd.dst[15] = in_sub; cd.n4[15] = 262144 / 4;
    cvt_multi<<<dim3(1024, 16), blk, 0, stream>>>(cd);

    init_inv<<<16, blk, 0, stream>>>(inv);
    scatter_inv<<<4, blk, 0, stream>>>(inv, ind_pair, 1024);

    auto gemm = [&](int tile, const u16* A, int lda, int aOffB, int aOffH,
                    const u16* B, int ldb, int bOffB, int bOffH,
                    float* Cf, u16* Ch, int ldc, long cOffB, long cOffH,
                    const float* bias, const float* r1, const float* r2,
                    float scale, int relu, int M, int N, int K, int batch) {
        if (tile == 64)
            mfma_gemm<64, 64><<<dim3(N / 64, M / 64, batch), blk, 0, stream>>>(
                A, lda, aOffB, aOffH, B, ldb, bOffB, bOffH, Cf, Ch, ldc, cOffB, cOffH,
                bias, r1, r2, scale, relu, K);
        else
            mfma_gemm<128, 128><<<dim3(N / 128, M / 128, batch), blk, 0, stream>>>(
                A, lda, aOffB, aOffH, B, ldb, bOffB, bOffH, Cf, Ch, ldc, cOffB, cOffH,
                bias, r1, r2, scale, relu, K);
    };
    // P @ V as NT GEMM on transposed V: att[(i*2+b)*512 + h*64 + d]
    auto pv = [&](const u16* V, int ldv, int L, int S) {
        vtrans<<<dim3(S / 64, 16), blk, 0, stream>>>(V, ldv, vtb, S);
        const int LS = L * S;
        gemm(64, probs, S, LS, 2 * LS, vtb, S, 64 * S, 128 * S,
             nullptr, attb, 1024, 512L, 64L,
             nullptr, nullptr, nullptr, 1.f, 0, L, 64, S, 16);
    };

    // ================= self-attention (pair) =================
    gemm(128, in_spb, 512, 0, 0, wb[0], 512, 0, 0, nullptr, qkvb, 1536, 0, 0,
         bi_sa, nullptr, nullptr, 1.f, 0, 2048, 1536, 512, 1);
    gemm(128, qkvb, 3072, 1536, 64, qkvb + 512, 3072, 1536, 64, nullptr, probs,
         1024, 1048576L, 2097152L, nullptr, nullptr, nullptr, 0.125f, 0, 1024, 1024, 64, 16);
    softmax_bf<<<16384, blk, 0, stream>>>(probs, 1024);
    pv(qkvb + 1024, 1536, 1024, 1024);
    gemm(64, attb, 512, 0, 0, wb[1], 512, 0, 0, tmp0f, nullptr, 512, 0, 0,
         bo_sa, in_sp, nullptr, 1.f, 0, 2048, 512, 512, 1);
    ln512<<<2048, blk, 0, stream>>>(tmp0f, g1, be1, spf, spb);

    // ================= self-attention (unary) =================
    gemm(64, in_sub, 512, 0, 0, wb[2], 512, 0, 0, nullptr, qkvb, 1536, 0, 0,
         bi_san, nullptr, nullptr, 1.f, 0, 512, 1536, 512, 1);
    gemm(64, qkvb, 3072, 1536, 64, qkvb + 512, 3072, 1536, 64, nullptr, probs,
         256, 65536L, 131072L, nullptr, nullptr, nullptr, 0.125f, 0, 256, 256, 64, 16);
    softmax_bf<<<4096, blk, 0, stream>>>(probs, 256);
    pv(qkvb + 1024, 1536, 256, 256);
    gemm(64, attb, 512, 0, 0, wb[3], 512, 0, 0, tmp0f, nullptr, 512, 0, 0,
         bo_san, in_su, nullptr, 1.f, 0, 512, 512, 512, 1);
    ln512<<<512, blk, 0, stream>>>(tmp0f, g1u, be1u, suf, sub);

    // ================= gathers =================
    gather_rows_bf<<<2048, blk, 0, stream>>>(ge2eb, spf, in_ep, ind_e2e, inv, 524288);
    gather_rows_bf<<<2048, blk, 0, stream>>>(gn2eb, spf, in_ep, ind_n2e, inv, 524288);

    // ================= e2e cross-attention =================
    gemm(64, spb, 512, 0, 0, wb[4], 512, 0, 0, nullptr, qkvb, 512, 0, 0,
         bi_e2e, nullptr, nullptr, 1.f, 0, 2048, 512, 512, 1);
    gemm(128, ge2eb, 512, 0, 0, wb[4] + 262144, 512, 0, 0, nullptr, kvb, 1024, 0, 0,
         bi_e2e + 512, nullptr, nullptr, 1.f, 0, 4096, 1024, 512, 1);
    gemm(128, qkvb, 1024, 512, 64, kvb, 2048, 1024, 64, nullptr, probs,
         2048, 2097152L, 4194304L, nullptr, nullptr, nullptr, 0.125f, 0, 1024, 2048, 64, 16);
    softmax_bf<<<16384, blk, 0, stream>>>(probs, 2048);
    pv(kvb + 512, 1024, 1024, 2048);
    avg_softmax<<<2048, blk, 0, stream>>>(probs, 1024, 2048, out_w1, out_w2);
    gemm(64, attb, 512, 0, 0, wb[5], 512, 0, 0, tmp0f, nullptr, 512, 0, 0,
         bo_e2e, spf, nullptr, 2.f, 0, 2048, 512, 512, 1);
    ln512<<<2048, blk, 0, stream>>>(tmp0f, g2, be2, tmp1f, tmp1b);
    // FFN (pair)
    gemm(128, tmp1b, 512, 0, 0, wb[10], 512, 0, 0, nullptr, ffnb, 2048, 0, 0,
         b1f, nullptr, nullptr, 1.f, 1, 2048, 2048, 512, 1);
    gemm(64, ffnb, 2048, 0, 0, wb[11], 2048, 0, 0, tmp0f, nullptr, 512, 0, 0,
         b2f, tmp1f, nullptr, 1.f, 0, 2048, 512, 2048, 1);
    ln512<<<2048, blk, 0, stream>>>(tmp0f, g3, be3, out_up, nullptr);

    // ================= n2e cross-attention =================
    gemm(64, sub, 512, 0, 0, wb[6], 512, 0, 0, nullptr, qkvb, 512, 0, 0,
         bi_n2e, nullptr, nullptr, 1.f, 0, 512, 512, 512, 1);
    gemm(128, gn2eb, 512, 0, 0, wb[6] + 262144, 512, 0, 0, nullptr, kvb, 1024, 0, 0,
         bi_n2e + 512, nullptr, nullptr, 1.f, 0, 4096, 1024, 512, 1);
    gemm(128, qkvb, 1024, 512, 64, kvb, 2048, 1024, 64, nullptr, probs,
         2048, 524288L, 1048576L, nullptr, nullptr, nullptr, 0.125f, 0, 256, 2048, 64, 16);
    softmax_bf<<<4096, blk, 0, stream>>>(probs, 2048);
    pv(kvb + 512, 1024, 256, 2048);
    avg_softmax<<<512, blk, 0, stream>>>(probs, 256, 2048, out_w3, nullptr);
    gemm(64, attb, 512, 0, 0, wb[7], 512, 0, 0, upn2ef, nullptr, 512, 0, 0,
         bo_n2e, nullptr, nullptr, 1.f, 0, 512, 512, 512, 1);

    // ================= n2n self-attention =================
    gemm(64, sub, 512, 0, 0, wb[8], 512, 0, 0, nullptr, qkvb, 1536, 0, 0,
         bi_n2n, nullptr, nullptr, 1.f, 0, 512, 1536, 512, 1);
    gemm(64, qkvb, 3072, 1536, 64, qkvb + 512, 3072, 1536, 64, nullptr, probs,
         256, 65536L, 131072L, nullptr, nullptr, nullptr, 0.125f, 0, 256, 256, 64, 16);
    softmax_bf<<<4096, blk, 0, stream>>>(probs, 256);
    pv(qkvb + 1024, 1536, 256, 256);
    avg_softmax<<<512, blk, 0, stream>>>(probs, 256, 256, out_w4, nullptr);
    gemm(64, attb, 512, 0, 0, wb[9], 512, 0, 0, tmp0f, nullptr, 512, 0, 0,
         bo_n2n, suf, upn2ef, 1.f, 0, 512, 512, 512, 1);
    ln512<<<512, blk, 0, stream>>>(tmp0f, g2, be2, tmp1f, tmp1b);
    // FFN (unary)
    gemm(64, tmp1b, 512, 0, 0, wb[12], 512, 0, 0, nullptr, ffnb, 2048, 0, 0,
         b1fu, nullptr, nullptr, 1.f, 1, 512, 2048, 512, 1);
    gemm(64, ffnb, 2048, 0, 0, wb[13], 2048, 0, 0, tmp0f, nullptr, 512, 0, 0,
         b2fu, tmp1f, nullptr, 1.f, 0, 512, 512, 2048, 1);
    ln512<<<512, blk, 0, stream>>>(tmp0f, g3, be3, out_uu, nullptr);
}

// Round 6
// 759.319 us; speedup vs baseline: 8.7063x; 1.0320x over previous
//
#include <hip/hip_runtime.h>
#include <cstddef>

#define LN_EPS 1e-5f

typedef unsigned short u16;
typedef short short8 __attribute__((ext_vector_type(8)));
typedef float f32x4 __attribute__((ext_vector_type(4)));

__device__ __forceinline__ u16 f2bf(float f) {
    unsigned int u = __float_as_uint(f);
    u = (u + 0x7FFFu + ((u >> 16) & 1u)) >> 16;
    return (u16)u;
}
__device__ __forceinline__ float bf2f(u16 h) {
    return __uint_as_float((unsigned int)h << 16);
}

// ---------------------------------------------------------------------------
// Multi-tensor fp32 -> bf16 convert (weights + inputs), one launch.
// ---------------------------------------------------------------------------
struct CvtDesc {
    const float* src[16];
    u16* dst[16];
    int n4[16];
};
__global__ __launch_bounds__(256) void cvt_multi(CvtDesc d) {
    const int t = blockIdx.x * 256 + threadIdx.x;
    const int i = blockIdx.y;
    if (t >= d.n4[i]) return;
    const float4 v = ((const float4*)d.src[i])[t];
    ushort4 o;
    o.x = f2bf(v.x); o.y = f2bf(v.y); o.z = f2bf(v.z); o.w = f2bf(v.w);
    ((ushort4*)d.dst[i])[t] = o;
}

// ---------------------------------------------------------------------------
// bf16 MFMA NT GEMM, BMxBN tile, 4 waves (2x2), BK=32, 16x16x32 MFMA.
// C = scale*(A@B^T + bias) + res1 + res2 (+relu). Outputs fp32 and/or bf16.
// Batched over grid.z: bz -> (b = bz&1, h = bz>>1) offsets for A/B/C.
// EXPA: A rows are raw attention scores; apply p=exp(s-mx)*inv during LDS
// staging using per-row stats (softmax normalization deferred from a
// separate pass). Only valid for BM=64 (one row-chunk per thread).
// ---------------------------------------------------------------------------
template<int BM, int BN, bool EXPA>
__global__ __launch_bounds__(256) void mfma_gemm(
    const u16* __restrict__ A, int lda, int aOffB, int aOffH,
    const u16* __restrict__ B, int ldb, int bOffB, int bOffH,
    float* __restrict__ Cf, u16* __restrict__ Ch,
    int ldc, long cOffB, long cOffH,
    const float* __restrict__ bias,
    const float* __restrict__ res1, const float* __restrict__ res2,
    float scale, int relu, int K,
    const float2* __restrict__ stats, int statB, int statH)
{
    constexpr int MF = BM / 32;
    constexpr int NF = BN / 32;
    __shared__ u16 As[BM * 32];
    __shared__ u16 Bs[BN * 32];

    const int tid = threadIdx.x;
    const int wave = tid >> 6, lane = tid & 63;
    const int wm = wave >> 1, wn = wave & 1;
    const int m0 = blockIdx.y * BM, n0 = blockIdx.x * BN;
    const int bz = blockIdx.z, bb = bz & 1, hh = bz >> 1;
    const size_t aOff = (size_t)bb * aOffB + (size_t)hh * aOffH;
    const size_t bOff = (size_t)bb * bOffB + (size_t)hh * bOffH;
    const size_t cOff = (size_t)bb * cOffB + (size_t)hh * cOffH;

    f32x4 acc[MF][NF];
#pragma unroll
    for (int mf = 0; mf < MF; ++mf)
#pragma unroll
        for (int nf = 0; nf < NF; ++nf) acc[mf][nf] = (f32x4){0.f, 0.f, 0.f, 0.f};

    const int ar = tid >> 2, ac = (tid & 3) * 8;
    const int ml = lane & 15, kq = lane >> 4;

    float mxv = 0.f, invv = 1.f;
    if (EXPA) {
        const float2 st = stats[(size_t)bb * statB + (size_t)hh * statH + m0 + ar];
        mxv = st.x; invv = st.y;
    }

    for (int k0 = 0; k0 < K; k0 += 32) {
        __syncthreads();
#pragma unroll
        for (int c = 0; c < BM / 64; ++c) {
            const int r = ar + c * 64;
            short8 va = *(const short8*)&A[aOff + (size_t)(m0 + r) * lda + k0 + ac];
            if (EXPA) {
                short8 o;
#pragma unroll
                for (int j = 0; j < 8; ++j)
                    o[j] = (short)f2bf(__expf(bf2f((u16)va[j]) - mxv) * invv);
                va = o;
            }
            *(short8*)&As[r * 32 + ac] = va;
        }
#pragma unroll
        for (int c = 0; c < BN / 64; ++c) {
            const int r = ar + c * 64;
            *(short8*)&Bs[r * 32 + ac] =
                *(const short8*)&B[bOff + (size_t)(n0 + r) * ldb + k0 + ac];
        }
        __syncthreads();

        short8 af[MF], bfr[NF];
#pragma unroll
        for (int mf = 0; mf < MF; ++mf)
            af[mf] = *(const short8*)&As[(wm * (BM / 2) + mf * 16 + ml) * 32 + kq * 8];
#pragma unroll
        for (int nf = 0; nf < NF; ++nf)
            bfr[nf] = *(const short8*)&Bs[(wn * (BN / 2) + nf * 16 + ml) * 32 + kq * 8];
#pragma unroll
        for (int mf = 0; mf < MF; ++mf)
#pragma unroll
            for (int nf = 0; nf < NF; ++nf)
                acc[mf][nf] = __builtin_amdgcn_mfma_f32_16x16x32_bf16(
                    af[mf], bfr[nf], acc[mf][nf], 0, 0, 0);
    }

    const int rq = lane >> 4;
#pragma unroll
    for (int mf = 0; mf < MF; ++mf)
#pragma unroll
        for (int nf = 0; nf < NF; ++nf) {
            const int col = n0 + wn * (BN / 2) + nf * 16 + ml;
            const float bv = bias ? bias[col] : 0.f;
#pragma unroll
            for (int r = 0; r < 4; ++r) {
                const int row = m0 + wm * (BM / 2) + mf * 16 + rq * 4 + r;
                float v = scale * (acc[mf][nf][r] + bv);
                const size_t idx = cOff + (size_t)row * ldc + col;
                if (res1) v += res1[idx];
                if (res2) v += res2[idx];
                if (relu) v = fmaxf(v, 0.f);
                if (Cf) Cf[idx] = v;
                if (Ch) Ch[idx] = f2bf(v);
            }
        }
}

// ---------------------------------------------------------------------------
// Per-row softmax stats over bf16 score rows: stats[row] = (max, 1/sum_exp).
// grid = nRows; S <= 2048 (thread t owns elements [8t, 8t+8)).
// ---------------------------------------------------------------------------
__global__ __launch_bounds__(256) void rowstat(
    const u16* __restrict__ X, float2* __restrict__ st, int S)
{
    __shared__ float red[256];
    const int tid = threadIdx.x;
    const bool act = tid * 8 < S;
    const u16* xr = X + (size_t)blockIdx.x * S;
    float v[8];
    float lmax = -1e30f;
    if (act) {
        const short8 r8 = *(const short8*)&xr[tid * 8];
#pragma unroll
        for (int j = 0; j < 8; ++j) { v[j] = bf2f((u16)r8[j]); lmax = fmaxf(lmax, v[j]); }
    }
    red[tid] = lmax; __syncthreads();
    for (int s = 128; s; s >>= 1) {
        if (tid < s) red[tid] = fmaxf(red[tid], red[tid + s]);
        __syncthreads();
    }
    const float mx = red[0]; __syncthreads();
    float ls = 0.f;
    if (act) {
#pragma unroll
        for (int j = 0; j < 8; ++j) ls += __expf(v[j] - mx);
    }
    red[tid] = ls; __syncthreads();
    for (int s = 128; s; s >>= 1) {
        if (tid < s) red[tid] += red[tid + s];
        __syncthreads();
    }
    if (tid == 0) st[blockIdx.x] = make_float2(mx, 1.0f / red[0]);
}

// ---------------------------------------------------------------------------
// One-time V transpose: vT[bh][d][s] = V[(s*2+b)*ldv + h*64 + d]  (bf16).
// ---------------------------------------------------------------------------
__global__ __launch_bounds__(256) void vtrans(
    const u16* __restrict__ V, int ldv, u16* __restrict__ vT, int S)
{
    __shared__ u16 Vs[64 * 72];
    const int tid = threadIdx.x;
    const int s0 = blockIdx.x * 64;
    const int bh = blockIdx.y, b = bh & 1, h = bh >> 1;

#pragma unroll
    for (int c = 0; c < 2; ++c) {
        const int idx = tid + c * 256;
        const int sr = idx >> 3, dc = (idx & 7) * 8;
        *(short8*)&Vs[sr * 72 + dc] =
            *(const short8*)&V[(size_t)((s0 + sr) * 2 + b) * ldv + h * 64 + dc];
    }
    __syncthreads();
#pragma unroll
    for (int c = 0; c < 2; ++c) {
        const int idx = tid + c * 256;
        const int dr = idx >> 3, sc = (idx & 7) * 8;
        short8 o;
#pragma unroll
        for (int j = 0; j < 8; ++j) o[j] = (short)Vs[(sc + j) * 72 + dr];
        *(short8*)&vT[(size_t)bh * 64 * S + (size_t)dr * S + s0 + sc] = o;
    }
}

// ---------------------------------------------------------------------------
// Fused: head-average of (stats-normalized) probs from RAW scores + second
// softmax -> fp32 out (1 or 2 copies). grid = 2*L, blockIdx.x = b*L + i.
// ---------------------------------------------------------------------------
__global__ __launch_bounds__(256) void avg_softmax_f(
    const u16* __restrict__ P, const float2* __restrict__ st, int L, int S,
    float* __restrict__ out1, float* __restrict__ out2)
{
    __shared__ float red[256];
    const int tid = threadIdx.x;
    const bool act = tid * 8 < S;
    const int b = blockIdx.x / L, i = blockIdx.x % L;
    const size_t LS = (size_t)L * S;

    float acc[8] = {};
    if (act) {
#pragma unroll
        for (int h = 0; h < 8; ++h) {
            const int bh = h * 2 + b;
            const float2 s = st[(size_t)bh * L + i];
            const short8 r8 = *(const short8*)&P[(size_t)bh * LS + (size_t)i * S + tid * 8];
#pragma unroll
            for (int j = 0; j < 8; ++j)
                acc[j] += __expf(bf2f((u16)r8[j]) - s.x) * s.y;
        }
#pragma unroll
        for (int j = 0; j < 8; ++j) acc[j] *= 0.125f;
    }
    float lmax = -1e30f;
    if (act) {
#pragma unroll
        for (int j = 0; j < 8; ++j) lmax = fmaxf(lmax, acc[j]);
    }
    red[tid] = lmax; __syncthreads();
    for (int s = 128; s; s >>= 1) {
        if (tid < s) red[tid] = fmaxf(red[tid], red[tid + s]);
        __syncthreads();
    }
    const float mx = red[0]; __syncthreads();
    float e[8];
    float ls = 0.f;
    if (act) {
#pragma unroll
        for (int j = 0; j < 8; ++j) { e[j] = __expf(acc[j] - mx); ls += e[j]; }
    }
    red[tid] = ls; __syncthreads();
    for (int s = 128; s; s >>= 1) {
        if (tid < s) red[tid] += red[tid + s];
        __syncthreads();
    }
    const float inv = 1.0f / red[0];
    if (act) {
        const size_t base = (size_t)blockIdx.x * S + tid * 8;
        float4 o0, o1;
        o0.x = e[0] * inv; o0.y = e[1] * inv; o0.z = e[2] * inv; o0.w = e[3] * inv;
        o1.x = e[4] * inv; o1.y = e[5] * inv; o1.z = e[6] * inv; o1.w = e[7] * inv;
        *(float4*)&out1[base] = o0; *(float4*)&out1[base + 4] = o1;
        if (out2) { *(float4*)&out2[base] = o0; *(float4*)&out2[base + 4] = o1; }
    }
}

// ---------------------------------------------------------------------------
// LayerNorm over rows of 512; fp32 out + optional bf16 out.
// ---------------------------------------------------------------------------
__global__ __launch_bounds__(256) void ln512(
    const float* __restrict__ X, const float* __restrict__ g,
    const float* __restrict__ be, float* __restrict__ Yf, u16* __restrict__ Yb)
{
    __shared__ float red[256];
    const int r = blockIdx.x, tid = threadIdx.x;
    const float* xr = X + (size_t)r * 512;
    const float x0 = xr[tid], x1 = xr[tid + 256];
    red[tid] = x0 + x1; __syncthreads();
    for (int st = 128; st; st >>= 1) {
        if (tid < st) red[tid] += red[tid + st];
        __syncthreads();
    }
    const float mean = red[0] * (1.0f / 512.0f); __syncthreads();
    const float d0 = x0 - mean, d1 = x1 - mean;
    red[tid] = d0 * d0 + d1 * d1; __syncthreads();
    for (int st = 128; st; st >>= 1) {
        if (tid < st) red[tid] += red[tid + st];
        __syncthreads();
    }
    const float rstd = rsqrtf(red[0] * (1.0f / 512.0f) + LN_EPS);
    const float y0 = d0 * rstd * g[tid] + be[tid];
    const float y1 = d1 * rstd * g[tid + 256] + be[tid + 256];
    float* yr = Yf + (size_t)r * 512;
    yr[tid] = y0; yr[tid + 256] = y1;
    if (Yb) {
        u16* yb = Yb + (size_t)r * 512;
        yb[tid] = f2bf(y0); yb[tid + 256] = f2bf(y1);
    }
}

// ---------------------------------------------------------------------------
// pair assembly: inverse map + gather rows to bf16.
// ---------------------------------------------------------------------------
__global__ void init_inv(int* __restrict__ inv) {
    const int i = blockIdx.x * 256 + threadIdx.x;
    if (i < 4096) inv[i] = -1;
}
__global__ void scatter_inv(int* __restrict__ inv, const int* __restrict__ ind, int n) {
    const int i = blockIdx.x * 256 + threadIdx.x;
    if (i < n) inv[ind[i]] = i;
}
__global__ void gather_rows_bf(
    u16* __restrict__ dst, const float* __restrict__ spf,
    const float* __restrict__ ep, const int* __restrict__ ind,
    const int* __restrict__ inv, int total4)
{
    const int e = blockIdx.x * 256 + threadIdx.x;
    if (e >= total4) return;
    const int row = e >> 7, c = e & 127;
    const int j = row >> 1, b = row & 1;
    const int idx = ind[j];
    const int iv = inv[idx];
    const float4* src = (iv >= 0) ? (const float4*)(spf + (size_t)(iv * 2 + b) * 512)
                                  : (const float4*)(ep + (size_t)(idx * 2 + b) * 512);
    const float4 v = src[c];
    ushort4 o; o.x = f2bf(v.x); o.y = f2bf(v.y); o.z = f2bf(v.z); o.w = f2bf(v.w);
    ((ushort4*)dst)[e] = o;
}

// ---------------------------------------------------------------------------
extern "C" void kernel_launch(void* const* d_in, const int* in_sizes, int n_in,
                              void* d_out, int out_size, void* d_ws, size_t ws_size,
                              hipStream_t stream)
{
    (void)in_sizes; (void)n_in; (void)out_size; (void)ws_size;

    const float* in_sp = (const float*)d_in[0];
    const float* in_su = (const float*)d_in[1];
    const float* in_ep = (const float*)d_in[2];
    const int* ind_pair = (const int*)d_in[3];
    const int* ind_e2e  = (const int*)d_in[4];
    const int* ind_n2e  = (const int*)d_in[5];
    const float *Wi_sa  = (const float*)d_in[6],  *bi_sa  = (const float*)d_in[7];
    const float *Wo_sa  = (const float*)d_in[8],  *bo_sa  = (const float*)d_in[9];
    const float *Wi_san = (const float*)d_in[10], *bi_san = (const float*)d_in[11];
    const float *Wo_san = (const float*)d_in[12], *bo_san = (const float*)d_in[13];
    const float *Wi_e2e = (const float*)d_in[14], *bi_e2e = (const float*)d_in[15];
    const float *Wo_e2e = (const float*)d_in[16], *bo_e2e = (const float*)d_in[17];
    const float *Wi_n2e = (const float*)d_in[18], *bi_n2e = (const float*)d_in[19];
    const float *Wo_n2e = (const float*)d_in[20], *bo_n2e = (const float*)d_in[21];
    const float *Wi_n2n = (const float*)d_in[22], *bi_n2n = (const float*)d_in[23];
    const float *Wo_n2n = (const float*)d_in[24], *bo_n2n = (const float*)d_in[25];
    const float *W1  = (const float*)d_in[26], *b1f  = (const float*)d_in[27];
    const float *W2  = (const float*)d_in[28], *b2f  = (const float*)d_in[29];
    const float *W1u = (const float*)d_in[30], *b1fu = (const float*)d_in[31];
    const float *W2u = (const float*)d_in[32], *b2fu = (const float*)d_in[33];
    const float *g1  = (const float*)d_in[34], *g1u = (const float*)d_in[35];
    const float *g2  = (const float*)d_in[36], *g3  = (const float*)d_in[37];
    const float *be1 = (const float*)d_in[38], *be1u = (const float*)d_in[39];
    const float *be2 = (const float*)d_in[40], *be3  = (const float*)d_in[41];

    float* Wf = (float*)d_ws;
    size_t of = 0;
    auto af_ = [&](size_t n) { float* p = Wf + of; of += n; return p; };
    float* spf    = af_((size_t)2048 * 512);
    float* suf    = af_((size_t)512 * 512);
    float* tmp0f  = af_((size_t)2048 * 512);
    float* tmp1f  = af_((size_t)2048 * 512);
    float* upn2ef = af_((size_t)512 * 512);
    float2* stats = (float2*)af_((size_t)2 * 16 * 1024);

    u16* Wu = (u16*)(Wf + of);
    size_t ou = 0;
    auto au_ = [&](size_t n) { u16* p = Wu + ou; ou += n; return p; };
    u16* in_spb = au_((size_t)2048 * 512);
    u16* in_sub = au_((size_t)512 * 512);
    u16* spb    = au_((size_t)2048 * 512);
    u16* sub    = au_((size_t)512 * 512);
    u16* ge2eb  = au_((size_t)4096 * 512);
    u16* gn2eb  = au_((size_t)4096 * 512);
    u16* qkvb   = au_((size_t)2048 * 1536);
    u16* kvb    = au_((size_t)4096 * 1024);
    u16* attb   = au_((size_t)2048 * 512);
    u16* tmp1b  = au_((size_t)2048 * 512);
    u16* ffnb   = au_((size_t)2048 * 2048);
    u16* vtb    = au_((size_t)16 * 64 * 2048);
    u16* probs  = au_((size_t)16 * 1024 * 2048);
    u16* wb[14];
    const int wsz[14] = {786432, 262144, 786432, 262144, 786432, 262144, 786432,
                         262144, 786432, 262144, 1048576, 1048576, 1048576, 1048576};
    for (int i = 0; i < 14; ++i) wb[i] = au_((size_t)wsz[i]);
    int* inv = (int*)(Wu + ou);

    float* out_uu = (float*)d_out;
    float* out_up = out_uu + 262144;
    float* out_w1 = out_up + 1048576;
    float* out_w2 = out_w1 + 4194304;
    float* out_w3 = out_w2 + 4194304;
    float* out_w4 = out_w3 + 1048576;

    const dim3 blk(256);

    CvtDesc cd;
    const float* wsrc[14] = {Wi_sa, Wo_sa, Wi_san, Wo_san, Wi_e2e, Wo_e2e, Wi_n2e,
                             Wo_n2e, Wi_n2n, Wo_n2n, W1, W2, W1u, W2u};
    for (int i = 0; i < 14; ++i) { cd.src[i] = wsrc[i]; cd.dst[i] = wb[i]; cd.n4[i] = wsz[i] / 4; }
    cd.src[14] = in_sp; cd.dst[14] = in_spb; cd.n4[14] = 1048576 / 4;
    cd.src[15] = in_su; cd.dst[15] = in_sub; cd.n4[15] = 262144 / 4;
    cvt_multi<<<dim3(1024, 16), blk, 0, stream>>>(cd);

    init_inv<<<16, blk, 0, stream>>>(inv);
    scatter_inv<<<4, blk, 0, stream>>>(inv, ind_pair, 1024);

    auto gemm = [&](int tile, const u16* A, int lda, int aOffB, int aOffH,
                    const u16* B, int ldb, int bOffB, int bOffH,
                    float* Cf, u16* Ch, int ldc, long cOffB, long cOffH,
                    const float* bias, const float* r1, const float* r2,
                    float scale, int relu, int M, int N, int K, int batch) {
        if (tile == 64)
            mfma_gemm<64, 64, false><<<dim3(N / 64, M / 64, batch), blk, 0, stream>>>(
                A, lda, aOffB, aOffH, B, ldb, bOffB, bOffH, Cf, Ch, ldc, cOffB, cOffH,
                bias, r1, r2, scale, relu, K, nullptr, 0, 0);
        else
            mfma_gemm<128, 128, false><<<dim3(N / 128, M / 128, batch), blk, 0, stream>>>(
                A, lda, aOffB, aOffH, B, ldb, bOffB, bOffH, Cf, Ch, ldc, cOffB, cOffH,
                bias, r1, r2, scale, relu, K, nullptr, 0, 0);
    };
    // P @ V from RAW scores: rowstat -> vtrans -> EXPA GEMM (softmax fused
    // into A-staging). att[(i*2+b)*512 + h*64 + d].
    auto pv = [&](const u16* V, int ldv, int L, int S) {
        rowstat<<<16 * L, blk, 0, stream>>>(probs, stats, S);
        vtrans<<<dim3(S / 64, 16), blk, 0, stream>>>(V, ldv, vtb, S);
        const int LS = L * S;
        mfma_gemm<64, 64, true><<<dim3(1, L / 64, 16), blk, 0, stream>>>(
            probs, S, LS, 2 * LS, vtb, S, 64 * S, 128 * S,
            nullptr, attb, 1024, 512L, 64L,
            nullptr, nullptr, nullptr, 1.f, 0, S, stats, L, 2 * L);
    };

    // ================= self-attention (pair) =================
    gemm(128, in_spb, 512, 0, 0, wb[0], 512, 0, 0, nullptr, qkvb, 1536, 0, 0,
         bi_sa, nullptr, nullptr, 1.f, 0, 2048, 1536, 512, 1);
    gemm(128, qkvb, 3072, 1536, 64, qkvb + 512, 3072, 1536, 64, nullptr, probs,
         1024, 1048576L, 2097152L, nullptr, nullptr, nullptr, 0.125f, 0, 1024, 1024, 64, 16);
    pv(qkvb + 1024, 1536, 1024, 1024);
    gemm(64, attb, 512, 0, 0, wb[1], 512, 0, 0, tmp0f, nullptr, 512, 0, 0,
         bo_sa, in_sp, nullptr, 1.f, 0, 2048, 512, 512, 1);
    ln512<<<2048, blk, 0, stream>>>(tmp0f, g1, be1, spf, spb);

    // ================= self-attention (unary) =================
    gemm(64, in_sub, 512, 0, 0, wb[2], 512, 0, 0, nullptr, qkvb, 1536, 0, 0,
         bi_san, nullptr, nullptr, 1.f, 0, 512, 1536, 512, 1);
    gemm(64, qkvb, 3072, 1536, 64, qkvb + 512, 3072, 1536, 64, nullptr, probs,
         256, 65536L, 131072L, nullptr, nullptr, nullptr, 0.125f, 0, 256, 256, 64, 16);
    pv(qkvb + 1024, 1536, 256, 256);
    gemm(64, attb, 512, 0, 0, wb[3], 512, 0, 0, tmp0f, nullptr, 512, 0, 0,
         bo_san, in_su, nullptr, 1.f, 0, 512, 512, 512, 1);
    ln512<<<512, blk, 0, stream>>>(tmp0f, g1u, be1u, suf, sub);

    // ================= gathers =================
    gather_rows_bf<<<2048, blk, 0, stream>>>(ge2eb, spf, in_ep, ind_e2e, inv, 524288);
    gather_rows_bf<<<2048, blk, 0, stream>>>(gn2eb, spf, in_ep, ind_n2e, inv, 524288);

    // ================= e2e cross-attention =================
    gemm(64, spb, 512, 0, 0, wb[4], 512, 0, 0, nullptr, qkvb, 512, 0, 0,
         bi_e2e, nullptr, nullptr, 1.f, 0, 2048, 512, 512, 1);
    gemm(128, ge2eb, 512, 0, 0, wb[4] + 262144, 512, 0, 0, nullptr, kvb, 1024, 0, 0,
         bi_e2e + 512, nullptr, nullptr, 1.f, 0, 4096, 1024, 512, 1);
    gemm(128, qkvb, 1024, 512, 64, kvb, 2048, 1024, 64, nullptr, probs,
         2048, 2097152L, 4194304L, nullptr, nullptr, nullptr, 0.125f, 0, 1024, 2048, 64, 16);
    pv(kvb + 512, 1024, 1024, 2048);
    avg_softmax_f<<<2048, blk, 0, stream>>>(probs, stats, 1024, 2048, out_w1, out_w2);
    gemm(64, attb, 512, 0, 0, wb[5], 512, 0, 0, tmp0f, nullptr, 512, 0, 0,
         bo_e2e, spf, nullptr, 2.f, 0, 2048, 512, 512, 1);
    ln512<<<2048, blk, 0, stream>>>(tmp0f, g2, be2, tmp1f, tmp1b);
    // FFN (pair)
    gemm(128, tmp1b, 512, 0, 0, wb[10], 512, 0, 0, nullptr, ffnb, 2048, 0, 0,
         b1f, nullptr, nullptr, 1.f, 1, 2048, 2048, 512, 1);
    gemm(64, ffnb, 2048, 0, 0, wb[11], 2048, 0, 0, tmp0f, nullptr, 512, 0, 0,
         b2f, tmp1f, nullptr, 1.f, 0, 2048, 512, 2048, 1);
    ln512<<<2048, blk, 0, stream>>>(tmp0f, g3, be3, out_up, nullptr);

    // ================= n2e cross-attention =================
    gemm(64, sub, 512, 0, 0, wb[6], 512, 0, 0, nullptr, qkvb, 512, 0, 0,
         bi_n2e, nullptr, nullptr, 1.f, 0, 512, 512, 512, 1);
    gemm(128, gn2eb, 512, 0, 0, wb[6] + 262144, 512, 0, 0, nullptr, kvb, 1024, 0, 0,
         bi_n2e + 512, nullptr, nullptr, 1.f, 0, 4096, 1024, 512, 1);
    gemm(128, qkvb, 1024, 512, 64, kvb, 2048, 1024, 64, nullptr, probs,
         2048, 524288L, 1048576L, nullptr, nullptr, nullptr, 0.125f, 0, 256, 2048, 64, 16);
    pv(kvb + 512, 1024, 256, 2048);
    avg_softmax_f<<<512, blk, 0, stream>>>(probs, stats, 256, 2048, out_w3, nullptr);
    gemm(64, attb, 512, 0, 0, wb[7], 512, 0, 0, upn2ef, nullptr, 512, 0, 0,
         bo_n2e, nullptr, nullptr, 1.f, 0, 512, 512, 512, 1);

    // ================= n2n self-attention =================
    gemm(64, sub, 512, 0, 0, wb[8], 512, 0, 0, nullptr, qkvb, 1536, 0, 0,
         bi_n2n, nullptr, nullptr, 1.f, 0, 512, 1536, 512, 1);
    gemm(64, qkvb, 3072, 1536, 64, qkvb + 512, 3072, 1536, 64, nullptr, probs,
         256, 65536L, 131072L, nullptr, nullptr, nullptr, 0.125f, 0, 256, 256, 64, 16);
    pv(qkvb + 1024, 1536, 256, 256);
    avg_softmax_f<<<512, blk, 0, stream>>>(probs, stats, 256, 256, out_w4, nullptr);
    gemm(64, attb, 512, 0, 0, wb[9], 512, 0, 0, tmp0f, nullptr, 512, 0, 0,
         bo_n2n, suf, upn2ef, 1.f, 0, 512, 512, 512, 1);
    ln512<<<512, blk, 0, stream>>>(tmp0f, g2, be2, tmp1f, tmp1b);
    // FFN (unary)
    gemm(64, tmp1b, 512, 0, 0, wb[12], 512, 0, 0, nullptr, ffnb, 2048, 0, 0,
         b1fu, nullptr, nullptr, 1.f, 1, 512, 2048, 512, 1);
    gemm(64, ffnb, 2048, 0, 0, wb[13], 2048, 0, 0, tmp0f, nullptr, 512, 0, 0,
         b2fu, tmp1f, nullptr, 1.f, 0, 512, 512, 2048, 1);
    ln512<<<512, blk, 0, stream>>>(tmp0f, g3, be3, out_uu, nullptr);
}

// Round 7
// 676.327 us; speedup vs baseline: 9.7747x; 1.1227x over previous
//
#include <hip/hip_runtime.h>
#include <cstddef>

#define LN_EPS 1e-5f

typedef unsigned short u16;
typedef short short8 __attribute__((ext_vector_type(8)));
typedef float f32x4 __attribute__((ext_vector_type(4)));

__device__ __forceinline__ u16 f2bf(float f) {
    unsigned int u = __float_as_uint(f);
    u = (u + 0x7FFFu + ((u >> 16) & 1u)) >> 16;
    return (u16)u;
}
__device__ __forceinline__ float bf2f(u16 h) {
    return __uint_as_float((unsigned int)h << 16);
}

// ---------------------------------------------------------------------------
// Multi-tensor fp32 -> bf16 convert (weights + inputs), one launch.
// ---------------------------------------------------------------------------
struct CvtDesc {
    const float* src[16];
    u16* dst[16];
    int n4[16];
};
__global__ __launch_bounds__(256) void cvt_multi(CvtDesc d) {
    const int t = blockIdx.x * 256 + threadIdx.x;
    const int i = blockIdx.y;
    if (t >= d.n4[i]) return;
    const float4 v = ((const float4*)d.src[i])[t];
    ushort4 o;
    o.x = f2bf(v.x); o.y = f2bf(v.y); o.z = f2bf(v.z); o.w = f2bf(v.w);
    ((ushort4*)d.dst[i])[t] = o;
}

// ---------------------------------------------------------------------------
// bf16 MFMA NT GEMM, BMxBN tile, 4 waves (2x2), BK=32, 16x16x32 MFMA.
// LDS rows padded to 40 u16 (80 B) to break bank aliasing; K-loop prefetches
// the next chunk into registers before the barrier (overlaps MFMA section).
// C = scale*(A@B^T + bias) + res1 + res2 (+relu). Outputs fp32 and/or bf16.
// Batched over grid.z: bz -> (b = bz&1, h = bz>>1) offsets for A/B/C.
// ---------------------------------------------------------------------------
template<int BM, int BN>
__global__ __launch_bounds__(256) void mfma_gemm(
    const u16* __restrict__ A, int lda, int aOffB, int aOffH,
    const u16* __restrict__ B, int ldb, int bOffB, int bOffH,
    float* __restrict__ Cf, u16* __restrict__ Ch,
    int ldc, long cOffB, long cOffH,
    const float* __restrict__ bias,
    const float* __restrict__ res1, const float* __restrict__ res2,
    float scale, int relu, int K)
{
    constexpr int MF = BM / 32;
    constexpr int NF = BN / 32;
    constexpr int MC = BM / 64;
    constexpr int NC = BN / 64;
    __shared__ u16 As[BM * 40];
    __shared__ u16 Bs[BN * 40];

    const int tid = threadIdx.x;
    const int wave = tid >> 6, lane = tid & 63;
    const int wm = wave >> 1, wn = wave & 1;
    const int m0 = blockIdx.y * BM, n0 = blockIdx.x * BN;
    const int bz = blockIdx.z, bb = bz & 1, hh = bz >> 1;
    const size_t aOff = (size_t)bb * aOffB + (size_t)hh * aOffH;
    const size_t bOff = (size_t)bb * bOffB + (size_t)hh * bOffH;
    const size_t cOff = (size_t)bb * cOffB + (size_t)hh * cOffH;

    f32x4 acc[MF][NF];
#pragma unroll
    for (int mf = 0; mf < MF; ++mf)
#pragma unroll
        for (int nf = 0; nf < NF; ++nf) acc[mf][nf] = (f32x4){0.f, 0.f, 0.f, 0.f};

    const int ar = tid >> 2, ac = (tid & 3) * 8;
    const int ml = lane & 15, kq = lane >> 4;

    short8 aN[MC], bN[NC];
#pragma unroll
    for (int c = 0; c < MC; ++c)
        aN[c] = *(const short8*)&A[aOff + (size_t)(m0 + ar + c * 64) * lda + ac];
#pragma unroll
    for (int c = 0; c < NC; ++c)
        bN[c] = *(const short8*)&B[bOff + (size_t)(n0 + ar + c * 64) * ldb + ac];

    for (int k0 = 0; k0 < K; k0 += 32) {
        short8 aS[MC], bS[NC];
#pragma unroll
        for (int c = 0; c < MC; ++c) aS[c] = aN[c];
#pragma unroll
        for (int c = 0; c < NC; ++c) bS[c] = bN[c];
        if (k0 + 32 < K) {
#pragma unroll
            for (int c = 0; c < MC; ++c)
                aN[c] = *(const short8*)&A[aOff + (size_t)(m0 + ar + c * 64) * lda + k0 + 32 + ac];
#pragma unroll
            for (int c = 0; c < NC; ++c)
                bN[c] = *(const short8*)&B[bOff + (size_t)(n0 + ar + c * 64) * ldb + k0 + 32 + ac];
        }
        __syncthreads();
#pragma unroll
        for (int c = 0; c < MC; ++c) *(short8*)&As[(ar + c * 64) * 40 + ac] = aS[c];
#pragma unroll
        for (int c = 0; c < NC; ++c) *(short8*)&Bs[(ar + c * 64) * 40 + ac] = bS[c];
        __syncthreads();

        short8 af[MF], bfr[NF];
#pragma unroll
        for (int mf = 0; mf < MF; ++mf)
            af[mf] = *(const short8*)&As[(wm * (BM / 2) + mf * 16 + ml) * 40 + kq * 8];
#pragma unroll
        for (int nf = 0; nf < NF; ++nf)
            bfr[nf] = *(const short8*)&Bs[(wn * (BN / 2) + nf * 16 + ml) * 40 + kq * 8];
#pragma unroll
        for (int mf = 0; mf < MF; ++mf)
#pragma unroll
            for (int nf = 0; nf < NF; ++nf)
                acc[mf][nf] = __builtin_amdgcn_mfma_f32_16x16x32_bf16(
                    af[mf], bfr[nf], acc[mf][nf], 0, 0, 0);
    }

    const int rq = lane >> 4;
#pragma unroll
    for (int mf = 0; mf < MF; ++mf)
#pragma unroll
        for (int nf = 0; nf < NF; ++nf) {
            const int col = n0 + wn * (BN / 2) + nf * 16 + ml;
            const float bv = bias ? bias[col] : 0.f;
#pragma unroll
            for (int r = 0; r < 4; ++r) {
                const int row = m0 + wm * (BM / 2) + mf * 16 + rq * 4 + r;
                float v = scale * (acc[mf][nf][r] + bv);
                const size_t idx = cOff + (size_t)row * ldc + col;
                if (res1) v += res1[idx];
                if (res2) v += res2[idx];
                if (relu) v = fmaxf(v, 0.f);
                if (Cf) Cf[idx] = v;
                if (Ch) Ch[idx] = f2bf(v);
            }
        }
}

// ---------------------------------------------------------------------------
// Fused PV: per block = (64 q-rows, one bh). Pass 1 streams the block's raw
// bf16 score rows once, computing online softmax stats (max, 1/sum) -> LDS
// + global stats (for avg_softmax_f). Pass 2 = MFMA K-loop over S with
// exp(s-m)*inv applied at LDS-staging time; next chunk register-prefetched.
// att[(i*2+b)*512 + h*64 + d] (bf16).  vT: [bh][64][S].
// ---------------------------------------------------------------------------
__global__ __launch_bounds__(256) void pv_fused(
    const u16* __restrict__ P, const u16* __restrict__ vT,
    u16* __restrict__ att, float2* __restrict__ stats, int L, int S)
{
    __shared__ u16 As[64 * 40];
    __shared__ u16 Bs[64 * 40];
    __shared__ float rm[64][5];
    __shared__ float rs[64][5];
    __shared__ float smax[64], sinv[64];

    const int tid = threadIdx.x;
    const int wave = tid >> 6, lane = tid & 63;
    const int wm = wave >> 1, wn = wave & 1;
    const int i0 = blockIdx.x * 64;
    const int bz = blockIdx.y, bb = bz & 1, hh = bz >> 1;
    const u16* Pb = P + (size_t)bz * L * S + (size_t)i0 * S;
    const u16* Vb = vT + (size_t)bz * 64 * S;

    const int r = tid >> 2, q = tid & 3, ac = q * 8;
    const int ml = lane & 15, kq = lane >> 4;

    // ---- pass 1: online (m, s) over this thread's quarter-row
    const int chunk = S >> 2;
    const u16* rowp = Pb + (size_t)r * S + q * chunk;
    float m = -1e30f, s = 0.f;
    for (int c = 0; c < chunk; c += 8) {
        const short8 v8 = *(const short8*)&rowp[c];
        float m8 = -1e30f;
        float v[8];
#pragma unroll
        for (int j = 0; j < 8; ++j) { v[j] = bf2f((u16)v8[j]); m8 = fmaxf(m8, v[j]); }
        float s8 = 0.f;
#pragma unroll
        for (int j = 0; j < 8; ++j) s8 += __expf(v[j] - m8);
        const float nm = fmaxf(m, m8);
        s = s * __expf(m - nm) + s8 * __expf(m8 - nm);
        m = nm;
    }
    rm[r][q] = m; rs[r][q] = s;
    __syncthreads();
    if (q == 0) {
        float mm = rm[r][0], ss = rs[r][0];
#pragma unroll
        for (int j = 1; j < 4; ++j) {
            const float nm = fmaxf(mm, rm[r][j]);
            ss = ss * __expf(mm - nm) + rs[r][j] * __expf(rm[r][j] - nm);
            mm = nm;
        }
        const float iv = 1.0f / ss;
        smax[r] = mm; sinv[r] = iv;
        stats[(size_t)bz * L + i0 + r] = make_float2(mm, iv);
    }
    __syncthreads();
    const float mxv = smax[r], invv = sinv[r];

    // ---- pass 2: MFMA K-loop with fused exp at staging + register prefetch
    f32x4 acc[2][2];
#pragma unroll
    for (int mf = 0; mf < 2; ++mf)
#pragma unroll
        for (int nf = 0; nf < 2; ++nf) acc[mf][nf] = (f32x4){0.f, 0.f, 0.f, 0.f};

    short8 aN = *(const short8*)&Pb[(size_t)r * S + ac];
    short8 bN = *(const short8*)&Vb[(size_t)r * S + ac];
    for (int k0 = 0; k0 < S; k0 += 32) {
        short8 aS;
#pragma unroll
        for (int j = 0; j < 8; ++j)
            aS[j] = (short)f2bf(__expf(bf2f((u16)aN[j]) - mxv) * invv);
        const short8 bS = bN;
        if (k0 + 32 < S) {
            aN = *(const short8*)&Pb[(size_t)r * S + k0 + 32 + ac];
            bN = *(const short8*)&Vb[(size_t)r * S + k0 + 32 + ac];
        }
        __syncthreads();
        *(short8*)&As[r * 40 + ac] = aS;
        *(short8*)&Bs[r * 40 + ac] = bS;
        __syncthreads();

        short8 af[2], bfr[2];
#pragma unroll
        for (int mf = 0; mf < 2; ++mf)
            af[mf] = *(const short8*)&As[(wm * 32 + mf * 16 + ml) * 40 + kq * 8];
#pragma unroll
        for (int nf = 0; nf < 2; ++nf)
            bfr[nf] = *(const short8*)&Bs[(wn * 32 + nf * 16 + ml) * 40 + kq * 8];
#pragma unroll
        for (int mf = 0; mf < 2; ++mf)
#pragma unroll
            for (int nf = 0; nf < 2; ++nf)
                acc[mf][nf] = __builtin_amdgcn_mfma_f32_16x16x32_bf16(
                    af[mf], bfr[nf], acc[mf][nf], 0, 0, 0);
    }

    const int rq = lane >> 4;
#pragma unroll
    for (int mf = 0; mf < 2; ++mf)
#pragma unroll
        for (int nf = 0; nf < 2; ++nf) {
            const int d = wn * 32 + nf * 16 + ml;
#pragma unroll
            for (int rr = 0; rr < 4; ++rr) {
                const int i = i0 + wm * 32 + mf * 16 + rq * 4 + rr;
                att[((size_t)i * 2 + bb) * 512 + hh * 64 + d] = f2bf(acc[mf][nf][rr]);
            }
        }
}

// ---------------------------------------------------------------------------
// One-time V transpose: vT[bh][d][s] = V[(s*2+b)*ldv + h*64 + d]  (bf16).
// ---------------------------------------------------------------------------
__global__ __launch_bounds__(256) void vtrans(
    const u16* __restrict__ V, int ldv, u16* __restrict__ vT, int S)
{
    __shared__ u16 Vs[64 * 72];
    const int tid = threadIdx.x;
    const int s0 = blockIdx.x * 64;
    const int bh = blockIdx.y, b = bh & 1, h = bh >> 1;

#pragma unroll
    for (int c = 0; c < 2; ++c) {
        const int idx = tid + c * 256;
        const int sr = idx >> 3, dc = (idx & 7) * 8;
        *(short8*)&Vs[sr * 72 + dc] =
            *(const short8*)&V[(size_t)((s0 + sr) * 2 + b) * ldv + h * 64 + dc];
    }
    __syncthreads();
#pragma unroll
    for (int c = 0; c < 2; ++c) {
        const int idx = tid + c * 256;
        const int dr = idx >> 3, sc = (idx & 7) * 8;
        short8 o;
#pragma unroll
        for (int j = 0; j < 8; ++j) o[j] = (short)Vs[(sc + j) * 72 + dr];
        *(short8*)&vT[(size_t)bh * 64 * S + (size_t)dr * S + s0 + sc] = o;
    }
}

// ---------------------------------------------------------------------------
// Fused: head-average of (stats-normalized) probs from RAW scores + second
// softmax -> fp32 out (1 or 2 copies). grid = 2*L, blockIdx.x = b*L + i.
// ---------------------------------------------------------------------------
__global__ __launch_bounds__(256) void avg_softmax_f(
    const u16* __restrict__ P, const float2* __restrict__ st, int L, int S,
    float* __restrict__ out1, float* __restrict__ out2)
{
    __shared__ float red[256];
    const int tid = threadIdx.x;
    const bool act = tid * 8 < S;
    const int b = blockIdx.x / L, i = blockIdx.x % L;
    const size_t LS = (size_t)L * S;

    float acc[8] = {};
    if (act) {
#pragma unroll
        for (int h = 0; h < 8; ++h) {
            const int bh = h * 2 + b;
            const float2 s = st[(size_t)bh * L + i];
            const short8 r8 = *(const short8*)&P[(size_t)bh * LS + (size_t)i * S + tid * 8];
#pragma unroll
            for (int j = 0; j < 8; ++j)
                acc[j] += __expf(bf2f((u16)r8[j]) - s.x) * s.y;
        }
#pragma unroll
        for (int j = 0; j < 8; ++j) acc[j] *= 0.125f;
    }
    float lmax = -1e30f;
    if (act) {
#pragma unroll
        for (int j = 0; j < 8; ++j) lmax = fmaxf(lmax, acc[j]);
    }
    red[tid] = lmax; __syncthreads();
    for (int s = 128; s; s >>= 1) {
        if (tid < s) red[tid] = fmaxf(red[tid], red[tid + s]);
        __syncthreads();
    }
    const float mx = red[0]; __syncthreads();
    float e[8];
    float ls = 0.f;
    if (act) {
#pragma unroll
        for (int j = 0; j < 8; ++j) { e[j] = __expf(acc[j] - mx); ls += e[j]; }
    }
    red[tid] = ls; __syncthreads();
    for (int s = 128; s; s >>= 1) {
        if (tid < s) red[tid] += red[tid + s];
        __syncthreads();
    }
    const float inv = 1.0f / red[0];
    if (act) {
        const size_t base = (size_t)blockIdx.x * S + tid * 8;
        float4 o0, o1;
        o0.x = e[0] * inv; o0.y = e[1] * inv; o0.z = e[2] * inv; o0.w = e[3] * inv;
        o1.x = e[4] * inv; o1.y = e[5] * inv; o1.z = e[6] * inv; o1.w = e[7] * inv;
        *(float4*)&out1[base] = o0; *(float4*)&out1[base + 4] = o1;
        if (out2) { *(float4*)&out2[base] = o0; *(float4*)&out2[base + 4] = o1; }
    }
}

// ---------------------------------------------------------------------------
// LayerNorm over rows of 512; fp32 out + optional bf16 out.
// ---------------------------------------------------------------------------
__global__ __launch_bounds__(256) void ln512(
    const float* __restrict__ X, const float* __restrict__ g,
    const float* __restrict__ be, float* __restrict__ Yf, u16* __restrict__ Yb)
{
    __shared__ float red[256];
    const int r = blockIdx.x, tid = threadIdx.x;
    const float* xr = X + (size_t)r * 512;
    const float x0 = xr[tid], x1 = xr[tid + 256];
    red[tid] = x0 + x1; __syncthreads();
    for (int st = 128; st; st >>= 1) {
        if (tid < st) red[tid] += red[tid + st];
        __syncthreads();
    }
    const float mean = red[0] * (1.0f / 512.0f); __syncthreads();
    const float d0 = x0 - mean, d1 = x1 - mean;
    red[tid] = d0 * d0 + d1 * d1; __syncthreads();
    for (int st = 128; st; st >>= 1) {
        if (tid < st) red[tid] += red[tid + st];
        __syncthreads();
    }
    const float rstd = rsqrtf(red[0] * (1.0f / 512.0f) + LN_EPS);
    const float y0 = d0 * rstd * g[tid] + be[tid];
    const float y1 = d1 * rstd * g[tid + 256] + be[tid + 256];
    float* yr = Yf + (size_t)r * 512;
    yr[tid] = y0; yr[tid + 256] = y1;
    if (Yb) {
        u16* yb = Yb + (size_t)r * 512;
        yb[tid] = f2bf(y0); yb[tid + 256] = f2bf(y1);
    }
}

// ---------------------------------------------------------------------------
// pair assembly: inverse map + gather rows to bf16.
// ---------------------------------------------------------------------------
__global__ void init_inv(int* __restrict__ inv) {
    const int i = blockIdx.x * 256 + threadIdx.x;
    if (i < 4096) inv[i] = -1;
}
__global__ void scatter_inv(int* __restrict__ inv, const int* __restrict__ ind, int n) {
    const int i = blockIdx.x * 256 + threadIdx.x;
    if (i < n) inv[ind[i]] = i;
}
__global__ void gather_rows_bf(
    u16* __restrict__ dst, const float* __restrict__ spf,
    const float* __restrict__ ep, const int* __restrict__ ind,
    const int* __restrict__ inv, int total4)
{
    const int e = blockIdx.x * 256 + threadIdx.x;
    if (e >= total4) return;
    const int row = e >> 7, c = e & 127;
    const int j = row >> 1, b = row & 1;
    const int idx = ind[j];
    const int iv = inv[idx];
    const float4* src = (iv >= 0) ? (const float4*)(spf + (size_t)(iv * 2 + b) * 512)
                                  : (const float4*)(ep + (size_t)(idx * 2 + b) * 512);
    const float4 v = src[c];
    ushort4 o; o.x = f2bf(v.x); o.y = f2bf(v.y); o.z = f2bf(v.z); o.w = f2bf(v.w);
    ((ushort4*)dst)[e] = o;
}

// ---------------------------------------------------------------------------
extern "C" void kernel_launch(void* const* d_in, const int* in_sizes, int n_in,
                              void* d_out, int out_size, void* d_ws, size_t ws_size,
                              hipStream_t stream)
{
    (void)in_sizes; (void)n_in; (void)out_size; (void)ws_size;

    const float* in_sp = (const float*)d_in[0];
    const float* in_su = (const float*)d_in[1];
    const float* in_ep = (const float*)d_in[2];
    const int* ind_pair = (const int*)d_in[3];
    const int* ind_e2e  = (const int*)d_in[4];
    const int* ind_n2e  = (const int*)d_in[5];
    const float *Wi_sa  = (const float*)d_in[6],  *bi_sa  = (const float*)d_in[7];
    const float *Wo_sa  = (const float*)d_in[8],  *bo_sa  = (const float*)d_in[9];
    const float *Wi_san = (const float*)d_in[10], *bi_san = (const float*)d_in[11];
    const float *Wo_san = (const float*)d_in[12], *bo_san = (const float*)d_in[13];
    const float *Wi_e2e = (const float*)d_in[14], *bi_e2e = (const float*)d_in[15];
    const float *Wo_e2e = (const float*)d_in[16], *bo_e2e = (const float*)d_in[17];
    const float *Wi_n2e = (const float*)d_in[18], *bi_n2e = (const float*)d_in[19];
    const float *Wo_n2e = (const float*)d_in[20], *bo_n2e = (const float*)d_in[21];
    const float *Wi_n2n = (const float*)d_in[22], *bi_n2n = (const float*)d_in[23];
    const float *Wo_n2n = (const float*)d_in[24], *bo_n2n = (const float*)d_in[25];
    const float *W1  = (const float*)d_in[26], *b1f  = (const float*)d_in[27];
    const float *W2  = (const float*)d_in[28], *b2f  = (const float*)d_in[29];
    const float *W1u = (const float*)d_in[30], *b1fu = (const float*)d_in[31];
    const float *W2u = (const float*)d_in[32], *b2fu = (const float*)d_in[33];
    const float *g1  = (const float*)d_in[34], *g1u = (const float*)d_in[35];
    const float *g2  = (const float*)d_in[36], *g3  = (const float*)d_in[37];
    const float *be1 = (const float*)d_in[38], *be1u = (const float*)d_in[39];
    const float *be2 = (const float*)d_in[40], *be3  = (const float*)d_in[41];

    float* Wf = (float*)d_ws;
    size_t of = 0;
    auto af_ = [&](size_t n) { float* p = Wf + of; of += n; return p; };
    float* spf    = af_((size_t)2048 * 512);
    float* suf    = af_((size_t)512 * 512);
    float* tmp0f  = af_((size_t)2048 * 512);
    float* tmp1f  = af_((size_t)2048 * 512);
    float* upn2ef = af_((size_t)512 * 512);
    float2* stats = (float2*)af_((size_t)2 * 16 * 1024);

    u16* Wu = (u16*)(Wf + of);
    size_t ou = 0;
    auto au_ = [&](size_t n) { u16* p = Wu + ou; ou += n; return p; };
    u16* in_spb = au_((size_t)2048 * 512);
    u16* in_sub = au_((size_t)512 * 512);
    u16* spb    = au_((size_t)2048 * 512);
    u16* sub    = au_((size_t)512 * 512);
    u16* ge2eb  = au_((size_t)4096 * 512);
    u16* gn2eb  = au_((size_t)4096 * 512);
    u16* qkvb   = au_((size_t)2048 * 1536);
    u16* kvb    = au_((size_t)4096 * 1024);
    u16* attb   = au_((size_t)2048 * 512);
    u16* tmp1b  = au_((size_t)2048 * 512);
    u16* ffnb   = au_((size_t)2048 * 2048);
    u16* vtb    = au_((size_t)16 * 64 * 2048);
    u16* probs  = au_((size_t)16 * 1024 * 2048);
    u16* wb[14];
    const int wsz[14] = {786432, 262144, 786432, 262144, 786432, 262144, 786432,
                         262144, 786432, 262144, 1048576, 1048576, 1048576, 1048576};
    for (int i = 0; i < 14; ++i) wb[i] = au_((size_t)wsz[i]);
    int* inv = (int*)(Wu + ou);

    float* out_uu = (float*)d_out;
    float* out_up = out_uu + 262144;
    float* out_w1 = out_up + 1048576;
    float* out_w2 = out_w1 + 4194304;
    float* out_w3 = out_w2 + 4194304;
    float* out_w4 = out_w3 + 1048576;

    const dim3 blk(256);

    CvtDesc cd;
    const float* wsrc[14] = {Wi_sa, Wo_sa, Wi_san, Wo_san, Wi_e2e, Wo_e2e, Wi_n2e,
                             Wo_n2e, Wi_n2n, Wo_n2n, W1, W2, W1u, W2u};
    for (int i = 0; i < 14; ++i) { cd.src[i] = wsrc[i]; cd.dst[i] = wb[i]; cd.n4[i] = wsz[i] / 4; }
    cd.src[14] = in_sp; cd.dst[14] = in_spb; cd.n4[14] = 1048576 / 4;
    cd.src[15] = in_su; cd.dst[15] = in_sub; cd.n4[15] = 262144 / 4;
    cvt_multi<<<dim3(1024, 16), blk, 0, stream>>>(cd);

    init_inv<<<16, blk, 0, stream>>>(inv);
    scatter_inv<<<4, blk, 0, stream>>>(inv, ind_pair, 1024);

    auto gemm = [&](int tile, const u16* A, int lda, int aOffB, int aOffH,
                    const u16* B, int ldb, int bOffB, int bOffH,
                    float* Cf, u16* Ch, int ldc, long cOffB, long cOffH,
                    const float* bias, const float* r1, const float* r2,
                    float scale, int relu, int M, int N, int K, int batch) {
        if (tile == 64)
            mfma_gemm<64, 64><<<dim3(N / 64, M / 64, batch), blk, 0, stream>>>(
                A, lda, aOffB, aOffH, B, ldb, bOffB, bOffH, Cf, Ch, ldc, cOffB, cOffH,
                bias, r1, r2, scale, relu, K);
        else
            mfma_gemm<128, 128><<<dim3(N / 128, M / 128, batch), blk, 0, stream>>>(
                A, lda, aOffB, aOffH, B, ldb, bOffB, bOffH, Cf, Ch, ldc, cOffB, cOffH,
                bias, r1, r2, scale, relu, K);
    };
    // P @ V from RAW scores: vtrans once, then fused stats+exp+MFMA kernel.
    auto pv = [&](const u16* V, int ldv, int L, int S) {
        vtrans<<<dim3(S / 64, 16), blk, 0, stream>>>(V, ldv, vtb, S);
        pv_fused<<<dim3(L / 64, 16), blk, 0, stream>>>(probs, vtb, attb, stats, L, S);
    };

    // ================= self-attention (pair) =================
    gemm(128, in_spb, 512, 0, 0, wb[0], 512, 0, 0, nullptr, qkvb, 1536, 0, 0,
         bi_sa, nullptr, nullptr, 1.f, 0, 2048, 1536, 512, 1);
    gemm(128, qkvb, 3072, 1536, 64, qkvb + 512, 3072, 1536, 64, nullptr, probs,
         1024, 1048576L, 2097152L, nullptr, nullptr, nullptr, 0.125f, 0, 1024, 1024, 64, 16);
    pv(qkvb + 1024, 1536, 1024, 1024);
    gemm(64, attb, 512, 0, 0, wb[1], 512, 0, 0, tmp0f, nullptr, 512, 0, 0,
         bo_sa, in_sp, nullptr, 1.f, 0, 2048, 512, 512, 1);
    ln512<<<2048, blk, 0, stream>>>(tmp0f, g1, be1, spf, spb);

    // ================= self-attention (unary) =================
    gemm(64, in_sub, 512, 0, 0, wb[2], 512, 0, 0, nullptr, qkvb, 1536, 0, 0,
         bi_san, nullptr, nullptr, 1.f, 0, 512, 1536, 512, 1);
    gemm(64, qkvb, 3072, 1536, 64, qkvb + 512, 3072, 1536, 64, nullptr, probs,
         256, 65536L, 131072L, nullptr, nullptr, nullptr, 0.125f, 0, 256, 256, 64, 16);
    pv(qkvb + 1024, 1536, 256, 256);
    gemm(64, attb, 512, 0, 0, wb[3], 512, 0, 0, tmp0f, nullptr, 512, 0, 0,
         bo_san, in_su, nullptr, 1.f, 0, 512, 512, 512, 1);
    ln512<<<512, blk, 0, stream>>>(tmp0f, g1u, be1u, suf, sub);

    // ================= gathers =================
    gather_rows_bf<<<2048, blk, 0, stream>>>(ge2eb, spf, in_ep, ind_e2e, inv, 524288);
    gather_rows_bf<<<2048, blk, 0, stream>>>(gn2eb, spf, in_ep, ind_n2e, inv, 524288);

    // ================= e2e cross-attention =================
    gemm(64, spb, 512, 0, 0, wb[4], 512, 0, 0, nullptr, qkvb, 512, 0, 0,
         bi_e2e, nullptr, nullptr, 1.f, 0, 2048, 512, 512, 1);
    gemm(128, ge2eb, 512, 0, 0, wb[4] + 262144, 512, 0, 0, nullptr, kvb, 1024, 0, 0,
         bi_e2e + 512, nullptr, nullptr, 1.f, 0, 4096, 1024, 512, 1);
    gemm(128, qkvb, 1024, 512, 64, kvb, 2048, 1024, 64, nullptr, probs,
         2048, 2097152L, 4194304L, nullptr, nullptr, nullptr, 0.125f, 0, 1024, 2048, 64, 16);
    pv(kvb + 512, 1024, 1024, 2048);
    avg_softmax_f<<<2048, blk, 0, stream>>>(probs, stats, 1024, 2048, out_w1, out_w2);
    gemm(64, attb, 512, 0, 0, wb[5], 512, 0, 0, tmp0f, nullptr, 512, 0, 0,
         bo_e2e, spf, nullptr, 2.f, 0, 2048, 512, 512, 1);
    ln512<<<2048, blk, 0, stream>>>(tmp0f, g2, be2, tmp1f, tmp1b);
    // FFN (pair)
    gemm(128, tmp1b, 512, 0, 0, wb[10], 512, 0, 0, nullptr, ffnb, 2048, 0, 0,
         b1f, nullptr, nullptr, 1.f, 1, 2048, 2048, 512, 1);
    gemm(64, ffnb, 2048, 0, 0, wb[11], 2048, 0, 0, tmp0f, nullptr, 512, 0, 0,
         b2f, tmp1f, nullptr, 1.f, 0, 2048, 512, 2048, 1);
    ln512<<<2048, blk, 0, stream>>>(tmp0f, g3, be3, out_up, nullptr);

    // ================= n2e cross-attention =================
    gemm(64, sub, 512, 0, 0, wb[6], 512, 0, 0, nullptr, qkvb, 512, 0, 0,
         bi_n2e, nullptr, nullptr, 1.f, 0, 512, 512, 512, 1);
    gemm(128, gn2eb, 512, 0, 0, wb[6] + 262144, 512, 0, 0, nullptr, kvb, 1024, 0, 0,
         bi_n2e + 512, nullptr, nullptr, 1.f, 0, 4096, 1024, 512, 1);
    gemm(128, qkvb, 1024, 512, 64, kvb, 2048, 1024, 64, nullptr, probs,
         2048, 524288L, 1048576L, nullptr, nullptr, nullptr, 0.125f, 0, 256, 2048, 64, 16);
    pv(kvb + 512, 1024, 256, 2048);
    avg_softmax_f<<<512, blk, 0, stream>>>(probs, stats, 256, 2048, out_w3, nullptr);
    gemm(64, attb, 512, 0, 0, wb[7], 512, 0, 0, upn2ef, nullptr, 512, 0, 0,
         bo_n2e, nullptr, nullptr, 1.f, 0, 512, 512, 512, 1);

    // ================= n2n self-attention =================
    gemm(64, sub, 512, 0, 0, wb[8], 512, 0, 0, nullptr, qkvb, 1536, 0, 0,
         bi_n2n, nullptr, nullptr, 1.f, 0, 512, 1536, 512, 1);
    gemm(64, qkvb, 3072, 1536, 64, qkvb + 512, 3072, 1536, 64, nullptr, probs,
         256, 65536L, 131072L, nullptr, nullptr, nullptr, 0.125f, 0, 256, 256, 64, 16);
    pv(qkvb + 1024, 1536, 256, 256);
    avg_softmax_f<<<512, blk, 0, stream>>>(probs, stats, 256, 256, out_w4, nullptr);
    gemm(64, attb, 512, 0, 0, wb[9], 512, 0, 0, tmp0f, nullptr, 512, 0, 0,
         bo_n2n, suf, upn2ef, 1.f, 0, 512, 512, 512, 1);
    ln512<<<512, blk, 0, stream>>>(tmp0f, g2, be2, tmp1f, tmp1b);
    // FFN (unary)
    gemm(64, tmp1b, 512, 0, 0, wb[12], 512, 0, 0, nullptr, ffnb, 2048, 0, 0,
         b1fu, nullptr, nullptr, 1.f, 1, 512, 2048, 512, 1);
    gemm(64, ffnb, 2048, 0, 0, wb[13], 2048, 0, 0, tmp0f, nullptr, 512, 0, 0,
         b2fu, tmp1f, nullptr, 1.f, 0, 512, 512, 2048, 1);
    ln512<<<512, blk, 0, stream>>>(tmp0f, g3, be3, out_uu, nullptr);
}